// Round 12
// baseline (2700.957 us; speedup 1.0000x reference)
//
#include <hip/hip_runtime.h>

using u16 = unsigned short;
using u32 = unsigned int;
using u64 = unsigned long long;
typedef __attribute__((ext_vector_type(8))) short s16x8;
typedef __attribute__((ext_vector_type(4))) short s16x4;
typedef __attribute__((ext_vector_type(4))) float f32x4;

__device__ __forceinline__ float bf2f(u16 u){ return __uint_as_float(((u32)u)<<16); }
__device__ __forceinline__ u16 f2bf(float f){
  u32 u = __float_as_uint(f);
  u += 0x7fffu + ((u>>16)&1u);
  return (u16)(u>>16);
}
__device__ __forceinline__ void gl_lds16(const void* g, void* l){
  __builtin_amdgcn_global_load_lds((const __attribute__((address_space(1))) void*)g,
                                   (__attribute__((address_space(3))) void*)l, 16, 0, 0);
}

// ---------------- fused: x fp32->bf16 + energy (blocks 0..8191) | weight cvt (blocks 8192..12290) ----------------
__global__ __launch_bounds__(256) void k_prep_all(const float* __restrict__ x, u16* __restrict__ xb,
                                                  float* __restrict__ energy,
                                                  const float* __restrict__ ipw, const float* __restrict__ ipb,
                                                  const float* __restrict__ outw,
                                                  u16* __restrict__ ipwb, u16* __restrict__ ipbb,
                                                  u16* __restrict__ outwb){
  int bid = blockIdx.x;
  if (bid < 8192){
    int tok = bid*4 + (threadIdx.x>>6);
    int lane = threadIdx.x & 63;
    const float* p = x + (size_t)tok*1024 + lane*16;
    float4 a[4];
    #pragma unroll
    for (int j=0;j<4;++j) a[j] = ((const float4*)p)[j];
    float s = 0.f;
    s16x8 o0, o1;
    #pragma unroll
    for (int j=0;j<2;++j){
      o0[j*4+0]=(short)f2bf(a[j].x); o0[j*4+1]=(short)f2bf(a[j].y);
      o0[j*4+2]=(short)f2bf(a[j].z); o0[j*4+3]=(short)f2bf(a[j].w);
    }
    #pragma unroll
    for (int j=0;j<2;++j){
      o1[j*4+0]=(short)f2bf(a[2+j].x); o1[j*4+1]=(short)f2bf(a[2+j].y);
      o1[j*4+2]=(short)f2bf(a[2+j].z); o1[j*4+3]=(short)f2bf(a[2+j].w);
    }
    #pragma unroll
    for (int j=0;j<4;++j){
      s += a[j].x*a[j].x + a[j].y*a[j].y + a[j].z*a[j].z + a[j].w*a[j].w;
    }
    u16* xo = xb + (size_t)tok*1024 + lane*16;
    *(s16x8*)xo = o0;
    *(s16x8*)(xo+8) = o1;
    #pragma unroll
    for (int off=32; off; off>>=1) s += __shfl_xor(s, off);
    if (lane==0) energy[tok] = s;
    return;
  }
  int b2 = bid - 8192;
  const float* src; u16* dst; int n; int base;
  if (b2 < 3072){ src=ipw; dst=ipwb; n=3145728; base=b2; }
  else if (b2 < 3075){ src=ipb; dst=ipbb; n=3072; base=b2-3072; }
  else { src=outw; dst=outwb; n=1048576; base=b2-3075; }
  int i = (base*256 + threadIdx.x)*4;
  if (i >= n) return;
  float4 v = *(const float4*)(src + i);
  s16x4 o;
  o[0]=(short)f2bf(v.x); o[1]=(short)f2bf(v.y); o[2]=(short)f2bf(v.z); o[3]=(short)f2bf(v.w);
  *(s16x4*)(dst + i) = o;
}

// ---------------- fused stats: colsum (blocks 0..255) + top-41 (blocks 256..263, 1 barrier/iter) ----------------
__global__ __launch_bounds__(256) void k_stats(const u16* __restrict__ xb, float* __restrict__ colsum,
                                               const float* __restrict__ energy, int* __restrict__ topk,
                                               int* __restrict__ sel){
  if (blockIdx.x < 256){
    int b = blockIdx.x >> 5, sc = blockIdx.x & 31;
    int t = threadIdx.x;
    float acc[4] = {0.f,0.f,0.f,0.f};
    for (int s = sc*128; s < sc*128+128; ++s){
      s16x4 v = *(const s16x4*)(xb + ((size_t)b*4096 + s)*1024 + t*4);
      #pragma unroll
      for (int i=0;i<4;++i) acc[i] += bf2f((u16)v[i]);
    }
    #pragma unroll
    for (int i=0;i<4;++i) atomicAdd(&colsum[b*1024 + t*4 + i], acc[i]);
    return;
  }
  int b = blockIdx.x - 256;
  int t = threadIdx.x;
  int lane = t & 63, wid = t >> 6;
  __shared__ u64 wmax[2][4];
  u64 v[16];
  #pragma unroll
  for (int i=0;i<16;++i){
    u32 tok = i*256 + t;
    float e = energy[b*4096 + tok];
    v[i] = ((u64)__float_as_uint(e) << 32) | (u32)(~tok);
    sel[b*4096 + tok] = -1;
  }
  __syncthreads();
  for (int it=0; it<41; ++it){
    u64 m = v[0];
    #pragma unroll
    for (int i=1;i<16;++i) m = v[i] > m ? v[i] : m;
    #pragma unroll
    for (int off=32; off; off>>=1){
      u64 o = __shfl_xor(m, off);
      m = o > m ? o : m;
    }
    if (lane==0) wmax[it&1][wid] = m;
    __syncthreads();
    u64 g = wmax[it&1][0];
    #pragma unroll
    for (int w=1;w<4;++w) g = wmax[it&1][w] > g ? wmax[it&1][w] : g;
    u32 tok = (~(u32)g) & 4095u;
    if (t==0){ topk[b*64+it] = (int)tok; sel[b*4096 + tok] = it; }
    #pragma unroll
    for (int i=0;i<16;++i){
      if ((u32)(i*256 + t) == tok) v[i] = 0;
    }
  }
}

// ---------------- gather selected x rows -> Aq bf16 [8*48][1024], zero-pad qi>=41 ----------------
__global__ __launch_bounds__(256) void k_gather_q(const float* __restrict__ x, const int* __restrict__ topk,
                                                  u16* __restrict__ Aq){
  int b = blockIdx.x, qi = blockIdx.y, t = threadIdx.x;
  size_t dst = ((size_t)(b*48+qi))*1024 + t*4;
  if (qi >= 41){ s16x4 z = {0,0,0,0}; *(s16x4*)&Aq[dst] = z; return; }
  int tok = topk[b*64+qi];
  float4 v = *(const float4*)(x + ((size_t)b*4096 + tok)*1024 + t*4);
  s16x4 o;
  o[0]=(short)f2bf(v.x); o[1]=(short)f2bf(v.y); o[2]=(short)f2bf(v.z); o[3]=(short)f2bf(v.w);
  *(s16x4*)&Aq[dst] = o;
}

// ---------------- generalized bf16 GEMM (m97 structure), kept for small-ws fallback KV path ----------------
__global__ __launch_bounds__(256) void k_gemm(const u16* __restrict__ A, const u16* __restrict__ Bk,
                                              const u16* __restrict__ Bv,
                                              const u16* __restrict__ biask, const u16* __restrict__ biasv,
                                              u16* __restrict__ C, int nbn, int ncols, int half, float cscale){
  __shared__ u16 As[128*64];
  __shared__ u16 Bs[128*64];
  const int tid = threadIdx.x;
  const int bn = blockIdx.x % nbn;
  const int bm = blockIdx.x / nbn;
  const int m0 = bm*128, n0 = bn*128;
  const u16* Bbase  = (n0 < half) ? (Bk + (size_t)n0*1024) : (Bv + (size_t)(n0-half)*1024);
  const u16* biasp  = (n0 < half) ? (biask + n0) : (biasv + (n0-half));
  const int lane = tid & 63;
  const int wave = tid >> 6;
  const int wr = wave >> 1, wc = wave & 1;
  const int fr = lane & 15;
  const int fq = lane >> 4;
  f32x4 acc[4][4] = {};
  for (int k0 = 0; k0 < 1024; k0 += 64){
    __syncthreads();
    #pragma unroll
    for (int j=0;j<4;++j){
      int idx = j*256 + tid;
      int r = idx>>3; int cc = (idx&7)*8;
      gl_lds16(A + (size_t)(m0+r)*1024 + k0 + cc, &As[r*64+cc]);
    }
    #pragma unroll
    for (int j=0;j<4;++j){
      int idx = j*256 + tid;
      int r = idx>>3; int cc = (idx&7)*8;
      gl_lds16(Bbase + (size_t)r*1024 + k0 + cc, &Bs[r*64+cc]);
    }
    __syncthreads();
    #pragma unroll
    for (int kk=0; kk<64; kk+=32){
      s16x8 af[4], bfv[4];
      #pragma unroll
      for (int m=0;m<4;++m) af[m] = *(const s16x8*)&As[(wr*64 + m*16 + fr)*64 + kk + fq*8];
      #pragma unroll
      for (int n=0;n<4;++n) bfv[n] = *(const s16x8*)&Bs[(wc*64 + n*16 + fr)*64 + kk + fq*8];
      #pragma unroll
      for (int m=0;m<4;++m)
        #pragma unroll
        for (int n=0;n<4;++n)
          acc[m][n] = __builtin_amdgcn_mfma_f32_16x16x32_bf16(af[m], bfv[n], acc[m][n], 0,0,0);
    }
  }
  #pragma unroll
  for (int n=0;n<4;++n){
    int cl = wc*64 + n*16 + fr;
    int col = n0 + cl;
    float bvv = bf2f(biasp[cl]);
    #pragma unroll
    for (int m=0;m<4;++m){
      int rowb = m0 + wr*64 + m*16 + fq*4;
      f32x4 v = acc[m][n];
      #pragma unroll
      for (int i=0;i<4;++i)
        C[(size_t)(rowb+i)*ncols + col] = f2bf((v[i]+bvv)*cscale);
    }
  }
}

// ---------------- split-K small GEMM: grid (24, 8), K=128/chunk; f32 atomicAdd accum (no bias) ----------------
__global__ __launch_bounds__(256) void k_gemm_sk(const u16* __restrict__ A, const u16* __restrict__ B,
                                                 float* __restrict__ Cacc){
  __shared__ u16 As[128*64];
  __shared__ u16 Bs[128*64];
  const int tid = threadIdx.x;
  const int bn = blockIdx.x & 7;
  const int bm = blockIdx.x >> 3;
  const int kc = blockIdx.y;
  const int m0 = bm*128, n0 = bn*128;
  const u16* Bbase = B + (size_t)n0*1024;
  const int lane = tid & 63;
  const int wave = tid >> 6;
  const int wr = wave >> 1, wc = wave & 1;
  const int fr = lane & 15;
  const int fq = lane >> 4;
  f32x4 acc[4][4] = {};
  for (int k0 = kc*128; k0 < kc*128+128; k0 += 64){
    __syncthreads();
    #pragma unroll
    for (int j=0;j<4;++j){
      int idx = j*256 + tid;
      int r = idx>>3; int cc = (idx&7)*8;
      gl_lds16(A + (size_t)(m0+r)*1024 + k0 + cc, &As[r*64+cc]);
    }
    #pragma unroll
    for (int j=0;j<4;++j){
      int idx = j*256 + tid;
      int r = idx>>3; int cc = (idx&7)*8;
      gl_lds16(Bbase + (size_t)r*1024 + k0 + cc, &Bs[r*64+cc]);
    }
    __syncthreads();
    #pragma unroll
    for (int kk=0; kk<64; kk+=32){
      s16x8 af[4], bfv[4];
      #pragma unroll
      for (int m=0;m<4;++m) af[m] = *(const s16x8*)&As[(wr*64 + m*16 + fr)*64 + kk + fq*8];
      #pragma unroll
      for (int n=0;n<4;++n) bfv[n] = *(const s16x8*)&Bs[(wc*64 + n*16 + fr)*64 + kk + fq*8];
      #pragma unroll
      for (int m=0;m<4;++m)
        #pragma unroll
        for (int n=0;n<4;++n)
          acc[m][n] = __builtin_amdgcn_mfma_f32_16x16x32_bf16(af[m], bfv[n], acc[m][n], 0,0,0);
    }
  }
  #pragma unroll
  for (int n=0;n<4;++n){
    int col = n0 + wc*64 + n*16 + fr;
    #pragma unroll
    for (int m=0;m<4;++m){
      int rowb = m0 + wr*64 + m*16 + fq*4;
      f32x4 v = acc[m][n];
      #pragma unroll
      for (int i=0;i<4;++i)
        atomicAdd(&Cacc[(size_t)(rowb+i)*1024 + col], v[i]);
    }
  }
}

// ================= KV GEMM v6: v4 body with 2-slot LDS (64 KiB) -> 2 blocks/CU (m114 cross-block overlap) =================
// Per iter T: {lgkm0;BAR  [all waves done reading slot(T&1) frags(T)]; stage(T+2)->slot(T&1);
//              vmcnt(8);BAR [all waves' T+1 loads landed; T+2's 8 fly]; read frags(T+1); MFMA(T) from regs}
__device__ __forceinline__ void stageA4(const u16* __restrict__ A, int m0, int k0, u16* slot, int tid){
  #pragma unroll
  for (int j=0;j<2;++j){
    int idx = j*512 + tid;
    int row = idx>>2;
    int sc = (idx&3) ^ ((row>>1)&3);
    gl_lds16(A + (size_t)(m0+row)*1024 + k0 + sc*8, slot + (size_t)idx*8);
  }
}
__device__ __forceinline__ void stageB4(const u16* __restrict__ B, int k0, u16* slot, int tid){
  #pragma unroll
  for (int j=0;j<2;++j){
    int idx = j*512 + tid;
    int row = idx>>2;
    int sc = (idx&3) ^ ((row>>1)&3);
    gl_lds16(B + (size_t)row*1024 + k0 + sc*8, slot + 8192 + (size_t)idx*8);
  }
}
__device__ __forceinline__ s16x8 fragA4(const u16* slot, int row, int fq){
  int pc = fq ^ ((row>>1)&3);
  return *(const s16x8*)(slot + row*32 + pc*8);
}
__device__ __forceinline__ s16x8 fragB4(const u16* slot, int row, int fq){
  int pc = fq ^ ((row>>1)&3);
  return *(const s16x8*)(slot + 8192 + row*32 + pc*8);
}

#define KSTEP6(T, CA, CB, NA, NB)                                              \
  asm volatile("s_waitcnt lgkmcnt(0)" ::: "memory");                           \
  __builtin_amdgcn_sched_barrier(0);                                           \
  __builtin_amdgcn_s_barrier();                                                \
  __builtin_amdgcn_sched_barrier(0);                                           \
  if ((T) < 30){                                                               \
    u16* ns = lds + ((T)&1)*16384;                                             \
    stageA4(A, m0, ((T)+2)*32, ns, tid);                                       \
    stageB4(Bbase, ((T)+2)*32, ns, tid);                                       \
  }                                                                            \
  if ((T) < 30)      { asm volatile("s_waitcnt vmcnt(8)" ::: "memory"); }      \
  else if ((T)==30)  { asm volatile("s_waitcnt vmcnt(0)" ::: "memory"); }      \
  __builtin_amdgcn_sched_barrier(0);                                           \
  __builtin_amdgcn_s_barrier();                                                \
  __builtin_amdgcn_sched_barrier(0);                                           \
  if ((T) < 31){                                                               \
    const u16* rs = lds + (((T)+1)&1)*16384;                                   \
    _Pragma("unroll")                                                          \
    for (int m=0;m<8;++m) NA[m] = fragA4(rs, wm*128 + m*16 + fr, fq);          \
    _Pragma("unroll")                                                          \
    for (int n=0;n<4;++n) NB[n] = fragB4(rs, wn*64 + n*16 + fr, fq);           \
  }                                                                            \
  __builtin_amdgcn_sched_barrier(0);                                           \
  __builtin_amdgcn_s_setprio(1);                                               \
  _Pragma("unroll")                                                            \
  for (int m=0;m<8;++m)                                                        \
    _Pragma("unroll")                                                          \
    for (int n=0;n<4;++n)                                                      \
      acc[m][n] = __builtin_amdgcn_mfma_f32_16x16x32_bf16(CA[m], CB[n], acc[m][n], 0,0,0); \
  __builtin_amdgcn_s_setprio(0);

__global__ __launch_bounds__(512, 4) void k_kvgemm6(const u16* __restrict__ A, const u16* __restrict__ Bk,
                                                    const u16* __restrict__ Bv,
                                                    const u16* __restrict__ biask, const u16* __restrict__ biasv,
                                                    u16* __restrict__ C){
  __shared__ u16 lds[2*16384];   // 64 KiB -> 2 blocks/CU
  const int tid = threadIdx.x;
  const int sbid = ((int)blockIdx.x & 7)*128 + ((int)blockIdx.x >> 3);   // T1 XCD swizzle, 1024%8==0
  const int bn = sbid & 7;
  const int bm = sbid >> 3;
  const int m0 = bm*256, n0 = bn*256;
  const u16* Bbase = (bn < 4) ? (Bk + (size_t)n0*1024) : (Bv + (size_t)(n0-1024)*1024);
  const u16* biasp = (bn < 4) ? (biask + n0) : (biasv + (n0-1024));
  const int lane = tid & 63, wid = tid >> 6;
  const int wm = wid >> 2, wn = wid & 3;
  const int fr = lane & 15, fq = lane >> 4;
  f32x4 acc[8][4] = {};
  s16x8 afr0[8], bfr0[4], afr1[8], bfr1[4];

  // prologue: tiles 0,1 -> slots 0,1; retire tile 0 (all waves); read frags(0)
  stageA4(A, m0, 0, lds, tid);          stageB4(Bbase, 0, lds, tid);
  stageA4(A, m0, 32, lds+16384, tid);   stageB4(Bbase, 32, lds+16384, tid);
  asm volatile("s_waitcnt vmcnt(8)" ::: "memory");
  __builtin_amdgcn_sched_barrier(0);
  __builtin_amdgcn_s_barrier();
  __builtin_amdgcn_sched_barrier(0);
  #pragma unroll
  for (int m=0;m<8;++m) afr0[m] = fragA4(lds, wm*128 + m*16 + fr, fq);
  #pragma unroll
  for (int n=0;n<4;++n) bfr0[n] = fragB4(lds, wn*64 + n*16 + fr, fq);

  for (int t=0; t<32; t+=2){
    KSTEP6(t,   afr0, bfr0, afr1, bfr1);
    KSTEP6(t+1, afr1, bfr1, afr0, bfr0);
  }

  // ---- epilogue: bias + bf16 -> LDS (64 KiB = one 128-row half), coalesced 16B stores ----
  u16* eLDS = lds;
  #pragma unroll
  for (int h=0; h<2; ++h){
    __syncthreads();
    if (wm == h){
      #pragma unroll
      for (int n=0;n<4;++n){
        int cl = wn*64 + n*16 + fr;
        float bvv = bf2f(biasp[cl]);
        #pragma unroll
        for (int m=0;m<8;++m){
          #pragma unroll
          for (int i=0;i<4;++i){
            int r = m*16 + fq*4 + i;
            eLDS[r*256 + cl] = f2bf(acc[m][n][i] + bvv);
          }
        }
      }
    }
    __syncthreads();
    #pragma unroll
    for (int j=0;j<8;++j){
      int e = j*512 + tid;
      int row = e >> 5, ch = e & 31;
      *(s16x8*)(C + (size_t)(m0 + h*128 + row)*2048 + n0 + ch*8) = *(const s16x8*)&eLDS[row*256 + ch*8];
    }
  }
}

// ---------------- flash attention: Q built from qacc f32 + bias + scale in-register ----------------
__global__ __launch_bounds__(64) void k_attn(const float* __restrict__ qacc, const float* __restrict__ bq,
                                             const u16* __restrict__ KV,
                                             float* __restrict__ part_ctx, float* __restrict__ part_ml,
                                             int G, int hg0, int ncols, int half, int nt, int NSP){
  const int b = blockIdx.x / G, hl = blockIdx.x % G;
  const int h = hg0 + hl;
  const int bh = b*16 + h;
  const int sp = blockIdx.y;
  const int lane = threadIdx.x;
  const int fr = lane & 15, fq = lane >> 4;
  __shared__ u16 k_lds[64*72];
  __shared__ u16 v_lds[64*72];
  __shared__ u16 p_lds[48*72];
  s16x8 af[3][2];
  #pragma unroll
  for (int m=0;m<3;++m)
    #pragma unroll
    for (int kk=0;kk<2;++kk){
      const float* qa = qacc + ((size_t)(b*48 + m*16 + fr))*1024 + h*64 + kk*32 + fq*8;
      const float* bp = bq + h*64 + kk*32 + fq*8;
      s16x8 f;
      #pragma unroll
      for (int j=0;j<8;++j) f[j] = (short)f2bf((qa[j] + bp[j])*0.125f);
      af[m][kk] = f;
    }
  f32x4 acc_o[3][4] = {};
  float m_run[3][4], l_run[3][4];
  #pragma unroll
  for (int m=0;m<3;++m)
    #pragma unroll
    for (int i=0;i<4;++i){ m_run[m][i] = -3e38f; l_run[m][i] = 0.f; }

  for (int it=0; it<nt; ++it){
    int s0 = (sp*nt + it)*64;
    __syncthreads();
    #pragma unroll
    for (int j=0;j<8;++j){
      int r = j*8 + (lane>>3);
      int sg = (lane&7)*8;
      const u16* kp = KV + ((size_t)(b*4096 + s0 + r))*ncols + hl*64 + sg;
      *(s16x8*)&k_lds[r*72+sg] = *(const s16x8*)kp;
      *(s16x8*)&v_lds[r*72+sg] = *(const s16x8*)(kp+half);
    }
    __syncthreads();
    f32x4 sc4[3][4] = {};
    #pragma unroll
    for (int kk=0;kk<2;++kk){
      s16x8 bk[4];
      #pragma unroll
      for (int n=0;n<4;++n)
        bk[n] = *(const s16x8*)&k_lds[(n*16+fr)*72 + kk*32 + fq*8];
      #pragma unroll
      for (int m=0;m<3;++m)
        #pragma unroll
        for (int n=0;n<4;++n)
          sc4[m][n] = __builtin_amdgcn_mfma_f32_16x16x32_bf16(af[m][kk], bk[n], sc4[m][n], 0,0,0);
    }
    #pragma unroll
    for (int m=0;m<3;++m){
      #pragma unroll
      for (int i=0;i<4;++i){
        float rmax = fmaxf(fmaxf(sc4[m][0][i], sc4[m][1][i]), fmaxf(sc4[m][2][i], sc4[m][3][i]));
        #pragma unroll
        for (int off=1; off<16; off<<=1) rmax = fmaxf(rmax, __shfl_xor(rmax, off));
        float mnew = fmaxf(m_run[m][i], rmax);
        float alpha = __expf(m_run[m][i] - mnew);
        m_run[m][i] = mnew;
        float rsum = 0.f;
        #pragma unroll
        for (int n=0;n<4;++n){
          float p = __expf(sc4[m][n][i] - mnew);
          rsum += p;
          p_lds[(m*16 + fq*4 + i)*72 + n*16 + fr] = f2bf(p);
        }
        #pragma unroll
        for (int off=1; off<16; off<<=1) rsum += __shfl_xor(rsum, off);
        l_run[m][i] = l_run[m][i]*alpha + rsum;
        #pragma unroll
        for (int n=0;n<4;++n) acc_o[m][n][i] *= alpha;
      }
    }
    __syncthreads();
    #pragma unroll
    for (int kk=0;kk<2;++kk){
      s16x8 ap[3];
      #pragma unroll
      for (int m=0;m<3;++m)
        ap[m] = *(const s16x8*)&p_lds[(m*16+fr)*72 + kk*32 + fq*8];
      #pragma unroll
      for (int n=0;n<4;++n){
        s16x8 bv;
        #pragma unroll
        for (int i2=0;i2<8;++i2)
          bv[i2] = (short)v_lds[(kk*32 + fq*8 + i2)*72 + n*16 + fr];
        #pragma unroll
        for (int m=0;m<3;++m)
          acc_o[m][n] = __builtin_amdgcn_mfma_f32_16x16x32_bf16(ap[m], bv, acc_o[m][n], 0,0,0);
      }
    }
  }
  size_t pbase = ((size_t)(bh*NSP + sp))*48*64;
  #pragma unroll
  for (int m=0;m<3;++m)
    #pragma unroll
    for (int n=0;n<4;++n)
      #pragma unroll
      for (int i=0;i<4;++i){
        int qi = m*16 + fq*4 + i, d = n*16 + fr;
        part_ctx[pbase + (size_t)qi*64 + d] = acc_o[m][n][i];
      }
  if (fr==0){
    #pragma unroll
    for (int m=0;m<3;++m)
      #pragma unroll
      for (int i=0;i<4;++i){
        int qi = m*16 + fq*4 + i;
        part_ml[((size_t)(bh*NSP+sp))*96 + qi*2+0] = m_run[m][i];
        part_ml[((size_t)(bh*NSP+sp))*96 + qi*2+1] = l_run[m][i];
      }
  }
}

// ---------------- combine NSP partials per (bh, qi), write bf16 ctx (zero-pad qi>=41) ----------------
__global__ __launch_bounds__(64) void k_combine(const float* __restrict__ part_ctx, const float* __restrict__ part_ml,
                                                u16* __restrict__ ctxb, int NSP){
  int bh = blockIdx.x, qi = blockIdx.y;
  int b = bh>>4, h = bh&15;
  int lane = threadIdx.x;
  size_t dst = ((size_t)(b*48+qi))*1024 + h*64 + lane;
  if (qi >= 41){ ctxb[dst] = 0; return; }
  float M = -3e38f;
  for (int p=0;p<NSP;++p)
    M = fmaxf(M, part_ml[((size_t)(bh*NSP+p))*96 + qi*2+0]);
  float l = 0.f, c = 0.f;
  for (int p=0;p<NSP;++p){
    float pm = part_ml[((size_t)(bh*NSP+p))*96 + qi*2+0];
    float pl = part_ml[((size_t)(bh*NSP+p))*96 + qi*2+1];
    float w = __expf(pm-M);
    l += pl*w;
    c += w * part_ctx[((size_t)(bh*NSP+p))*48*64 + (size_t)qi*64 + lane];
  }
  ctxb[dst] = f2bf(c / l);
}

// ---------------- finalize: selected rows = oacc + out_b (f32), others = per-batch mean ----------------
__global__ __launch_bounds__(256) void k_finalize(const float* __restrict__ oacc, const float* __restrict__ outb,
                                                  const float* __restrict__ colsum,
                                                  const int* __restrict__ sel, float* __restrict__ out){
  int row = blockIdx.x;
  int b = row >> 12;
  int t = threadIdx.x;
  int s = sel[row];
  float4 o;
  if (s >= 0){
    float4 a = *(const float4*)(oacc + ((size_t)(b*48+s))*1024 + t*4);
    float4 bb = *(const float4*)(outb + t*4);
    o.x = a.x+bb.x; o.y = a.y+bb.y; o.z = a.z+bb.z; o.w = a.w+bb.w;
  } else {
    o = *(const float4*)(colsum + b*1024 + t*4);
    o.x *= (1.f/4096.f); o.y *= (1.f/4096.f); o.z *= (1.f/4096.f); o.w *= (1.f/4096.f);
  }
  *(float4*)(out + (size_t)row*1024 + t*4) = o;
}

extern "C" void kernel_launch(void* const* d_in, const int* in_sizes, int n_in,
                              void* d_out, int out_size, void* d_ws, size_t ws_size,
                              hipStream_t stream) {
  const float* x    = (const float*)d_in[0];
  const float* ipw  = (const float*)d_in[1];
  const float* ipb  = (const float*)d_in[2];
  const float* outw = (const float*)d_in[3];
  const float* outb = (const float*)d_in[4];
  float* out = (float*)d_out;
  char* ws = (char*)d_ws;

  // ---- ws-adaptive config: G heads per KV chunk, NSP key-splits for attention ----
  const int cfgG[7]   = {16, 8, 4, 2, 1, 1, 1};
  const int cfgNSP[7] = {16,16,16,16,16, 4, 2};
  int G = 1, NSP = 2;
  size_t oXB=0,oWIP=0,oBIP=0,oWO=0,oEN=0,oCS=0,oQA=0,oOA=0,oTK=0,oSEL=0,oAQ=0,oCTXB=0,oPML=0,oPCTX=0,oKV=0;
  for (int ci=0; ci<7; ++ci){
    int g = cfgG[ci], nsp = cfgNSP[ci];
    size_t o = 0;
    size_t xb=o;   o += 67108864;            // xb    bf16[32768][1024]
    size_t wip=o;  o += 6291456;             // ipwb  bf16[3072][1024]
    size_t bip=o;  o += 6144;                // ipbb  bf16[3072]
    size_t wo=o;   o += 2097152;             // outwb bf16[1024][1024]
    size_t en=o;   o += 131072;              // energy f32[32768]
    size_t cs=o;   o += 32768;               // colsum f32[8*1024], contiguous with qacc+oacc for one memset
    size_t qa=o;   o += 1572864;             // qacc  f32[384][1024]
    size_t oa=o;   o += 1572864;             // oacc  f32[384][1024]
    size_t tk=o;   o += 2048;                // topk  int[8*64]
    size_t sl=o;   o += 131072;              // sel   int[32768]
    size_t aq=o;   o += 786432;              // Aq    bf16[384][1024]
    size_t cb=o;   o += 786432;              // ctxb  bf16[384][1024]
    size_t pm=o;   o += (size_t)nsp*49152;   // pml   f32[128*nsp*96]
    size_t pc=o;   o += (size_t)nsp*1572864; // pctx  f32[128*nsp*48*64]
    size_t kv=o;   o += (size_t)g*8388608;   // KV    bf16[32768][g*128]
    if (o <= ws_size || ci == 6){
      G=g; NSP=nsp;
      oXB=xb; oWIP=wip; oBIP=bip; oWO=wo; oEN=en; oCS=cs; oQA=qa; oOA=oa; oTK=tk; oSEL=sl;
      oAQ=aq; oCTXB=cb; oPML=pm; oPCTX=pc; oKV=kv;
      break;
    }
  }

  u16*   xb     = (u16*)(ws + oXB);
  u16*   ipwb   = (u16*)(ws + oWIP);
  u16*   ipbb   = (u16*)(ws + oBIP);
  u16*   outwb  = (u16*)(ws + oWO);
  float* energy = (float*)(ws + oEN);
  float* colsum = (float*)(ws + oCS);
  float* qacc   = (float*)(ws + oQA);
  float* oacc   = (float*)(ws + oOA);
  int*   topk   = (int*)(ws + oTK);
  int*   sel    = (int*)(ws + oSEL);
  u16*   Aq     = (u16*)(ws + oAQ);
  u16*   ctxb   = (u16*)(ws + oCTXB);
  float* pml    = (float*)(ws + oPML);
  float* pctx   = (float*)(ws + oPCTX);
  u16*   KV     = (u16*)(ws + oKV);

  hipMemsetAsync(colsum, 0, 32768 + 2*1572864, stream);

  k_prep_all <<<12291, 256, 0, stream>>>(x, xb, energy, ipw, ipb, outw, ipwb, ipbb, outwb);
  k_stats  <<<264, 256, 0, stream>>>(xb, colsum, energy, topk, sel);
  k_gather_q<<<dim3(8,48), 256, 0, stream>>>(x, topk, Aq);

  // Q = Aq @ Wq^T   split-K f32 accum; bias+scale folded into k_attn's fragment build
  k_gemm_sk <<<dim3(24,8), 256, 0, stream>>>(Aq, ipwb, qacc);

  if (G == 16){
    const int nt = 64/NSP;
    k_kvgemm6 <<<1024, 512, 0, stream>>>(xb,
        ipwb + (size_t)1024*1024, ipwb + (size_t)2048*1024,
        ipbb + 1024, ipbb + 2048, KV);
    k_attn <<<dim3(128, NSP), 64, 0, stream>>>(qacc, ipb, KV, pctx, pml, 16, 0, 2048, 1024, nt, NSP);
  } else {
    const int nchunk = 16 / G;
    const int ncols = G*128, half = G*64, nt = 64/NSP;
    for (int c=0; c<nchunk; ++c){
      int hg0 = c*G;
      k_gemm <<<G*256, 256, 0, stream>>>(
          xb,
          ipwb + (size_t)(1024 + hg0*64)*1024,
          ipwb + (size_t)(2048 + hg0*64)*1024,
          ipbb + 1024 + hg0*64,
          ipbb + 2048 + hg0*64,
          KV, G, ncols, half, 1.0f);
      k_attn <<<dim3(8*G, NSP), 64, 0, stream>>>(qacc, ipb, KV, pctx, pml, G, hg0, ncols, half, nt, NSP);
    }
  }

  k_combine<<<dim3(128,48), 64, 0, stream>>>(pctx, pml, ctxb, NSP);

  // out_sel = ctx @ Wo^T   split-K f32 accum, bias at finalize
  k_gemm_sk <<<dim3(24,8), 256, 0, stream>>>(ctxb, outwb, oacc);

  k_finalize<<<32768, 256, 0, stream>>>(oacc, outb, colsum, sel, out);
}

// Round 14
// 371.601 us; speedup vs baseline: 7.2684x; 7.2684x over previous
//
#include <hip/hip_runtime.h>

using u16 = unsigned short;
using u32 = unsigned int;
using u64 = unsigned long long;
typedef __attribute__((ext_vector_type(8))) short s16x8;
typedef __attribute__((ext_vector_type(4))) short s16x4;
typedef __attribute__((ext_vector_type(4))) float f32x4;

__device__ __forceinline__ float bf2f(u16 u){ return __uint_as_float(((u32)u)<<16); }
__device__ __forceinline__ u16 f2bf(float f){
  u32 u = __float_as_uint(f);
  u += 0x7fffu + ((u>>16)&1u);
  return (u16)(u>>16);
}
__device__ __forceinline__ void gl_lds16(const void* g, void* l){
  __builtin_amdgcn_global_load_lds((const __attribute__((address_space(1))) void*)g,
                                   (__attribute__((address_space(3))) void*)l, 16, 0, 0);
}

// ---------------- fused: x fp32->bf16 + energy (blocks 0..8191) | weight cvt (blocks 8192..12290) ----------------
__global__ __launch_bounds__(256) void k_prep_all(const float* __restrict__ x, u16* __restrict__ xb,
                                                  float* __restrict__ energy,
                                                  const float* __restrict__ ipw, const float* __restrict__ ipb,
                                                  const float* __restrict__ outw,
                                                  u16* __restrict__ ipwb, u16* __restrict__ ipbb,
                                                  u16* __restrict__ outwb){
  int bid = blockIdx.x;
  if (bid < 8192){
    int tok = bid*4 + (threadIdx.x>>6);
    int lane = threadIdx.x & 63;
    const float* p = x + (size_t)tok*1024 + lane*16;
    float4 a[4];
    #pragma unroll
    for (int j=0;j<4;++j) a[j] = ((const float4*)p)[j];
    float s = 0.f;
    s16x8 o0, o1;
    #pragma unroll
    for (int j=0;j<2;++j){
      o0[j*4+0]=(short)f2bf(a[j].x); o0[j*4+1]=(short)f2bf(a[j].y);
      o0[j*4+2]=(short)f2bf(a[j].z); o0[j*4+3]=(short)f2bf(a[j].w);
    }
    #pragma unroll
    for (int j=0;j<2;++j){
      o1[j*4+0]=(short)f2bf(a[2+j].x); o1[j*4+1]=(short)f2bf(a[2+j].y);
      o1[j*4+2]=(short)f2bf(a[2+j].z); o1[j*4+3]=(short)f2bf(a[2+j].w);
    }
    #pragma unroll
    for (int j=0;j<4;++j){
      s += a[j].x*a[j].x + a[j].y*a[j].y + a[j].z*a[j].z + a[j].w*a[j].w;
    }
    u16* xo = xb + (size_t)tok*1024 + lane*16;
    *(s16x8*)xo = o0;
    *(s16x8*)(xo+8) = o1;
    #pragma unroll
    for (int off=32; off; off>>=1) s += __shfl_xor(s, off);
    if (lane==0) energy[tok] = s;
    return;
  }
  int b2 = bid - 8192;
  const float* src; u16* dst; int n; int base;
  if (b2 < 3072){ src=ipw; dst=ipwb; n=3145728; base=b2; }
  else if (b2 < 3075){ src=ipb; dst=ipbb; n=3072; base=b2-3072; }
  else { src=outw; dst=outwb; n=1048576; base=b2-3075; }
  int i = (base*256 + threadIdx.x)*4;
  if (i >= n) return;
  float4 v = *(const float4*)(src + i);
  s16x4 o;
  o[0]=(short)f2bf(v.x); o[1]=(short)f2bf(v.y); o[2]=(short)f2bf(v.z); o[3]=(short)f2bf(v.w);
  *(s16x4*)(dst + i) = o;
}

// ---------------- fused stats: colsum (blocks 0..255) + top-41 (blocks 256..263, 1 barrier/iter) ----------------
__global__ __launch_bounds__(256) void k_stats(const u16* __restrict__ xb, float* __restrict__ colsum,
                                               const float* __restrict__ energy, int* __restrict__ topk,
                                               int* __restrict__ sel){
  if (blockIdx.x < 256){
    int b = blockIdx.x >> 5, sc = blockIdx.x & 31;
    int t = threadIdx.x;
    float acc[4] = {0.f,0.f,0.f,0.f};
    for (int s = sc*128; s < sc*128+128; ++s){
      s16x4 v = *(const s16x4*)(xb + ((size_t)b*4096 + s)*1024 + t*4);
      #pragma unroll
      for (int i=0;i<4;++i) acc[i] += bf2f((u16)v[i]);
    }
    #pragma unroll
    for (int i=0;i<4;++i) atomicAdd(&colsum[b*1024 + t*4 + i], acc[i]);
    return;
  }
  int b = blockIdx.x - 256;
  int t = threadIdx.x;
  int lane = t & 63, wid = t >> 6;
  __shared__ u64 wmax[2][4];
  u64 v[16];
  #pragma unroll
  for (int i=0;i<16;++i){
    u32 tok = i*256 + t;
    float e = energy[b*4096 + tok];
    v[i] = ((u64)__float_as_uint(e) << 32) | (u32)(~tok);
    sel[b*4096 + tok] = -1;
  }
  __syncthreads();
  for (int it=0; it<41; ++it){
    u64 m = v[0];
    #pragma unroll
    for (int i=1;i<16;++i) m = v[i] > m ? v[i] : m;
    #pragma unroll
    for (int off=32; off; off>>=1){
      u64 o = __shfl_xor(m, off);
      m = o > m ? o : m;
    }
    if (lane==0) wmax[it&1][wid] = m;
    __syncthreads();
    u64 g = wmax[it&1][0];
    #pragma unroll
    for (int w=1;w<4;++w) g = wmax[it&1][w] > g ? wmax[it&1][w] : g;
    u32 tok = (~(u32)g) & 4095u;
    if (t==0){ topk[b*64+it] = (int)tok; sel[b*4096 + tok] = it; }
    #pragma unroll
    for (int i=0;i<16;++i){
      if ((u32)(i*256 + t) == tok) v[i] = 0;
    }
  }
}

// ---------------- gather selected x rows -> Aq bf16 [8*48][1024], zero-pad qi>=41 ----------------
__global__ __launch_bounds__(256) void k_gather_q(const float* __restrict__ x, const int* __restrict__ topk,
                                                  u16* __restrict__ Aq){
  int b = blockIdx.x, qi = blockIdx.y, t = threadIdx.x;
  size_t dst = ((size_t)(b*48+qi))*1024 + t*4;
  if (qi >= 41){ s16x4 z = {0,0,0,0}; *(s16x4*)&Aq[dst] = z; return; }
  int tok = topk[b*64+qi];
  float4 v = *(const float4*)(x + ((size_t)b*4096 + tok)*1024 + t*4);
  s16x4 o;
  o[0]=(short)f2bf(v.x); o[1]=(short)f2bf(v.y); o[2]=(short)f2bf(v.z); o[3]=(short)f2bf(v.w);
  *(s16x4*)&Aq[dst] = o;
}

// ---------------- generalized bf16 GEMM (m97 structure), kept for small-ws fallback KV path ----------------
__global__ __launch_bounds__(256) void k_gemm(const u16* __restrict__ A, const u16* __restrict__ Bk,
                                              const u16* __restrict__ Bv,
                                              const u16* __restrict__ biask, const u16* __restrict__ biasv,
                                              u16* __restrict__ C, int nbn, int ncols, int half, float cscale){
  __shared__ u16 As[128*64];
  __shared__ u16 Bs[128*64];
  const int tid = threadIdx.x;
  const int bn = blockIdx.x % nbn;
  const int bm = blockIdx.x / nbn;
  const int m0 = bm*128, n0 = bn*128;
  const u16* Bbase  = (n0 < half) ? (Bk + (size_t)n0*1024) : (Bv + (size_t)(n0-half)*1024);
  const u16* biasp  = (n0 < half) ? (biask + n0) : (biasv + (n0-half));
  const int lane = tid & 63;
  const int wave = tid >> 6;
  const int wr = wave >> 1, wc = wave & 1;
  const int fr = lane & 15;
  const int fq = lane >> 4;
  f32x4 acc[4][4] = {};
  for (int k0 = 0; k0 < 1024; k0 += 64){
    __syncthreads();
    #pragma unroll
    for (int j=0;j<4;++j){
      int idx = j*256 + tid;
      int r = idx>>3; int cc = (idx&7)*8;
      gl_lds16(A + (size_t)(m0+r)*1024 + k0 + cc, &As[r*64+cc]);
    }
    #pragma unroll
    for (int j=0;j<4;++j){
      int idx = j*256 + tid;
      int r = idx>>3; int cc = (idx&7)*8;
      gl_lds16(Bbase + (size_t)r*1024 + k0 + cc, &Bs[r*64+cc]);
    }
    __syncthreads();
    #pragma unroll
    for (int kk=0; kk<64; kk+=32){
      s16x8 af[4], bfv[4];
      #pragma unroll
      for (int m=0;m<4;++m) af[m] = *(const s16x8*)&As[(wr*64 + m*16 + fr)*64 + kk + fq*8];
      #pragma unroll
      for (int n=0;n<4;++n) bfv[n] = *(const s16x8*)&Bs[(wc*64 + n*16 + fr)*64 + kk + fq*8];
      #pragma unroll
      for (int m=0;m<4;++m)
        #pragma unroll
        for (int n=0;n<4;++n)
          acc[m][n] = __builtin_amdgcn_mfma_f32_16x16x32_bf16(af[m], bfv[n], acc[m][n], 0,0,0);
    }
  }
  #pragma unroll
  for (int n=0;n<4;++n){
    int cl = wc*64 + n*16 + fr;
    int col = n0 + cl;
    float bvv = bf2f(biasp[cl]);
    #pragma unroll
    for (int m=0;m<4;++m){
      int rowb = m0 + wr*64 + m*16 + fq*4;
      f32x4 v = acc[m][n];
      #pragma unroll
      for (int i=0;i<4;++i)
        C[(size_t)(rowb+i)*ncols + col] = f2bf((v[i]+bvv)*cscale);
    }
  }
}

// ---------------- split-K small GEMM: grid (24, 8), K=128/chunk; f32 atomicAdd accum (no bias) ----------------
__global__ __launch_bounds__(256) void k_gemm_sk(const u16* __restrict__ A, const u16* __restrict__ B,
                                                 float* __restrict__ Cacc){
  __shared__ u16 As[128*64];
  __shared__ u16 Bs[128*64];
  const int tid = threadIdx.x;
  const int bn = blockIdx.x & 7;
  const int bm = blockIdx.x >> 3;
  const int kc = blockIdx.y;
  const int m0 = bm*128, n0 = bn*128;
  const u16* Bbase = B + (size_t)n0*1024;
  const int lane = tid & 63;
  const int wave = tid >> 6;
  const int wr = wave >> 1, wc = wave & 1;
  const int fr = lane & 15;
  const int fq = lane >> 4;
  f32x4 acc[4][4] = {};
  for (int k0 = kc*128; k0 < kc*128+128; k0 += 64){
    __syncthreads();
    #pragma unroll
    for (int j=0;j<4;++j){
      int idx = j*256 + tid;
      int r = idx>>3; int cc = (idx&7)*8;
      gl_lds16(A + (size_t)(m0+r)*1024 + k0 + cc, &As[r*64+cc]);
    }
    #pragma unroll
    for (int j=0;j<4;++j){
      int idx = j*256 + tid;
      int r = idx>>3; int cc = (idx&7)*8;
      gl_lds16(Bbase + (size_t)r*1024 + k0 + cc, &Bs[r*64+cc]);
    }
    __syncthreads();
    #pragma unroll
    for (int kk=0; kk<64; kk+=32){
      s16x8 af[4], bfv[4];
      #pragma unroll
      for (int m=0;m<4;++m) af[m] = *(const s16x8*)&As[(wr*64 + m*16 + fr)*64 + kk + fq*8];
      #pragma unroll
      for (int n=0;n<4;++n) bfv[n] = *(const s16x8*)&Bs[(wc*64 + n*16 + fr)*64 + kk + fq*8];
      #pragma unroll
      for (int m=0;m<4;++m)
        #pragma unroll
        for (int n=0;n<4;++n)
          acc[m][n] = __builtin_amdgcn_mfma_f32_16x16x32_bf16(af[m], bfv[n], acc[m][n], 0,0,0);
    }
  }
  #pragma unroll
  for (int n=0;n<4;++n){
    int col = n0 + wc*64 + n*16 + fr;
    #pragma unroll
    for (int m=0;m<4;++m){
      int rowb = m0 + wr*64 + m*16 + fq*4;
      f32x4 v = acc[m][n];
      #pragma unroll
      for (int i=0;i<4;++i)
        atomicAdd(&Cacc[(size_t)(rowb+i)*1024 + col], v[i]);
    }
  }
}

// ================= KV GEMM v6c: 2-slot LDS (64 KiB) -> 2 blocks/CU; vmcnt FIXED (4 loads/tile, not 8) =================
// Round-13 race: stage = 4 gl_lds/tile, so after issuing T+2 the counter is 8 -> vmcnt(8) waited for NOTHING
// and frag reads raced T+1's in-flight loads. Correct counts: steady vmcnt(4), tail vmcnt(0), prologue vmcnt(4).
__device__ __forceinline__ void stageA4(const u16* __restrict__ A, int m0, int k0, u16* slot, int tid){
  #pragma unroll
  for (int j=0;j<2;++j){
    int idx = j*512 + tid;
    int row = idx>>2;
    int sc = (idx&3) ^ ((row>>1)&3);
    gl_lds16(A + (size_t)(m0+row)*1024 + k0 + sc*8, slot + (size_t)idx*8);
  }
}
__device__ __forceinline__ void stageB4(const u16* __restrict__ B, int k0, u16* slot, int tid){
  #pragma unroll
  for (int j=0;j<2;++j){
    int idx = j*512 + tid;
    int row = idx>>2;
    int sc = (idx&3) ^ ((row>>1)&3);
    gl_lds16(B + (size_t)row*1024 + k0 + sc*8, slot + 8192 + (size_t)idx*8);
  }
}
__device__ __forceinline__ s16x8 fragA4(const u16* slot, int row, int fq){
  int pc = fq ^ ((row>>1)&3);
  return *(const s16x8*)(slot + row*32 + pc*8);
}
__device__ __forceinline__ s16x8 fragB4(const u16* slot, int row, int fq){
  int pc = fq ^ ((row>>1)&3);
  return *(const s16x8*)(slot + 8192 + row*32 + pc*8);
}

#define KSTEP6(T, CA, CB, NA, NB)                                              \
  asm volatile("s_waitcnt lgkmcnt(0)" ::: "memory");                           \
  __builtin_amdgcn_sched_barrier(0);                                           \
  __builtin_amdgcn_s_barrier();                                                \
  __builtin_amdgcn_sched_barrier(0);                                           \
  if ((T) < 30){                                                               \
    u16* ns = lds + ((T)&1)*16384;                                             \
    stageA4(A, m0, ((T)+2)*32, ns, tid);                                       \
    stageB4(Bbase, ((T)+2)*32, ns, tid);                                       \
  }                                                                            \
  if ((T) < 30)      { asm volatile("s_waitcnt vmcnt(4)" ::: "memory"); }      \
  else if ((T)==30)  { asm volatile("s_waitcnt vmcnt(0)" ::: "memory"); }      \
  __builtin_amdgcn_sched_barrier(0);                                           \
  __builtin_amdgcn_s_barrier();                                                \
  __builtin_amdgcn_sched_barrier(0);                                           \
  if ((T) < 31){                                                               \
    const u16* rs = lds + (((T)+1)&1)*16384;                                   \
    _Pragma("unroll")                                                          \
    for (int m=0;m<8;++m) NA[m] = fragA4(rs, wm*128 + m*16 + fr, fq);          \
    _Pragma("unroll")                                                          \
    for (int n=0;n<4;++n) NB[n] = fragB4(rs, wn*64 + n*16 + fr, fq);           \
  }                                                                            \
  __builtin_amdgcn_sched_barrier(0);                                           \
  __builtin_amdgcn_s_setprio(1);                                               \
  _Pragma("unroll")                                                            \
  for (int m=0;m<8;++m)                                                        \
    _Pragma("unroll")                                                          \
    for (int n=0;n<4;++n)                                                      \
      acc[m][n] = __builtin_amdgcn_mfma_f32_16x16x32_bf16(CA[m], CB[n], acc[m][n], 0,0,0); \
  __builtin_amdgcn_s_setprio(0);

__global__ __launch_bounds__(512) void k_kvgemm6(const u16* __restrict__ A, const u16* __restrict__ Bk,
                                                 const u16* __restrict__ Bv,
                                                 const u16* __restrict__ biask, const u16* __restrict__ biasv,
                                                 u16* __restrict__ C){
  __shared__ u16 lds[2*16384];   // 64 KiB -> 2 blocks/CU (LDS-limited), VGPR free (~128)
  const int tid = threadIdx.x;
  const int sbid = ((int)blockIdx.x & 7)*128 + ((int)blockIdx.x >> 3);   // T1 XCD swizzle, 1024%8==0
  const int bn = sbid & 7;
  const int bm = sbid >> 3;
  const int m0 = bm*256, n0 = bn*256;
  const u16* Bbase = (bn < 4) ? (Bk + (size_t)n0*1024) : (Bv + (size_t)(n0-1024)*1024);
  const u16* biasp = (bn < 4) ? (biask + n0) : (biasv + (n0-1024));
  const int lane = tid & 63, wid = tid >> 6;
  const int wm = wid >> 2, wn = wid & 3;
  const int fr = lane & 15, fq = lane >> 4;
  f32x4 acc[8][4] = {};
  s16x8 afr0[8], bfr0[4], afr1[8], bfr1[4];

  // prologue: tiles 0,1 -> slots 0,1 (4 loads each); vmcnt(4) retires tile 0's 4; read frags(0)
  stageA4(A, m0, 0, lds, tid);          stageB4(Bbase, 0, lds, tid);
  stageA4(A, m0, 32, lds+16384, tid);   stageB4(Bbase, 32, lds+16384, tid);
  asm volatile("s_waitcnt vmcnt(4)" ::: "memory");
  __builtin_amdgcn_sched_barrier(0);
  __builtin_amdgcn_s_barrier();
  __builtin_amdgcn_sched_barrier(0);
  #pragma unroll
  for (int m=0;m<8;++m) afr0[m] = fragA4(lds, wm*128 + m*16 + fr, fq);
  #pragma unroll
  for (int n=0;n<4;++n) bfr0[n] = fragB4(lds, wn*64 + n*16 + fr, fq);

  for (int t=0; t<32; t+=2){
    KSTEP6(t,   afr0, bfr0, afr1, bfr1);
    KSTEP6(t+1, afr1, bfr1, afr0, bfr0);
  }

  // ---- epilogue: bias + bf16 -> LDS (64 KiB = one 128-row half), coalesced 16B stores ----
  u16* eLDS = lds;
  #pragma unroll
  for (int h=0; h<2; ++h){
    __syncthreads();
    if (wm == h){
      #pragma unroll
      for (int n=0;n<4;++n){
        int cl = wn*64 + n*16 + fr;
        float bvv = bf2f(biasp[cl]);
        #pragma unroll
        for (int m=0;m<8;++m){
          #pragma unroll
          for (int i=0;i<4;++i){
            int r = m*16 + fq*4 + i;
            eLDS[r*256 + cl] = f2bf(acc[m][n][i] + bvv);
          }
        }
      }
    }
    __syncthreads();
    #pragma unroll
    for (int j=0;j<8;++j){
      int e = j*512 + tid;
      int row = e >> 5, ch = e & 31;
      *(s16x8*)(C + (size_t)(m0 + h*128 + row)*2048 + n0 + ch*8) = *(const s16x8*)&eLDS[row*256 + ch*8];
    }
  }
}

// ---------------- flash attention: Q built from qacc f32 + bias + scale in-register ----------------
__global__ __launch_bounds__(64) void k_attn(const float* __restrict__ qacc, const float* __restrict__ bq,
                                             const u16* __restrict__ KV,
                                             float* __restrict__ part_ctx, float* __restrict__ part_ml,
                                             int G, int hg0, int ncols, int half, int nt, int NSP){
  const int b = blockIdx.x / G, hl = blockIdx.x % G;
  const int h = hg0 + hl;
  const int bh = b*16 + h;
  const int sp = blockIdx.y;
  const int lane = threadIdx.x;
  const int fr = lane & 15, fq = lane >> 4;
  __shared__ u16 k_lds[64*72];
  __shared__ u16 v_lds[64*72];
  __shared__ u16 p_lds[48*72];
  s16x8 af[3][2];
  #pragma unroll
  for (int m=0;m<3;++m)
    #pragma unroll
    for (int kk=0;kk<2;++kk){
      const float* qa = qacc + ((size_t)(b*48 + m*16 + fr))*1024 + h*64 + kk*32 + fq*8;
      const float* bp = bq + h*64 + kk*32 + fq*8;
      s16x8 f;
      #pragma unroll
      for (int j=0;j<8;++j) f[j] = (short)f2bf((qa[j] + bp[j])*0.125f);
      af[m][kk] = f;
    }
  f32x4 acc_o[3][4] = {};
  float m_run[3][4], l_run[3][4];
  #pragma unroll
  for (int m=0;m<3;++m)
    #pragma unroll
    for (int i=0;i<4;++i){ m_run[m][i] = -3e38f; l_run[m][i] = 0.f; }

  for (int it=0; it<nt; ++it){
    int s0 = (sp*nt + it)*64;
    __syncthreads();
    #pragma unroll
    for (int j=0;j<8;++j){
      int r = j*8 + (lane>>3);
      int sg = (lane&7)*8;
      const u16* kp = KV + ((size_t)(b*4096 + s0 + r))*ncols + hl*64 + sg;
      *(s16x8*)&k_lds[r*72+sg] = *(const s16x8*)kp;
      *(s16x8*)&v_lds[r*72+sg] = *(const s16x8*)(kp+half);
    }
    __syncthreads();
    f32x4 sc4[3][4] = {};
    #pragma unroll
    for (int kk=0;kk<2;++kk){
      s16x8 bk[4];
      #pragma unroll
      for (int n=0;n<4;++n)
        bk[n] = *(const s16x8*)&k_lds[(n*16+fr)*72 + kk*32 + fq*8];
      #pragma unroll
      for (int m=0;m<3;++m)
        #pragma unroll
        for (int n=0;n<4;++n)
          sc4[m][n] = __builtin_amdgcn_mfma_f32_16x16x32_bf16(af[m][kk], bk[n], sc4[m][n], 0,0,0);
    }
    #pragma unroll
    for (int m=0;m<3;++m){
      #pragma unroll
      for (int i=0;i<4;++i){
        float rmax = fmaxf(fmaxf(sc4[m][0][i], sc4[m][1][i]), fmaxf(sc4[m][2][i], sc4[m][3][i]));
        #pragma unroll
        for (int off=1; off<16; off<<=1) rmax = fmaxf(rmax, __shfl_xor(rmax, off));
        float mnew = fmaxf(m_run[m][i], rmax);
        float alpha = __expf(m_run[m][i] - mnew);
        m_run[m][i] = mnew;
        float rsum = 0.f;
        #pragma unroll
        for (int n=0;n<4;++n){
          float p = __expf(sc4[m][n][i] - mnew);
          rsum += p;
          p_lds[(m*16 + fq*4 + i)*72 + n*16 + fr] = f2bf(p);
        }
        #pragma unroll
        for (int off=1; off<16; off<<=1) rsum += __shfl_xor(rsum, off);
        l_run[m][i] = l_run[m][i]*alpha + rsum;
        #pragma unroll
        for (int n=0;n<4;++n) acc_o[m][n][i] *= alpha;
      }
    }
    __syncthreads();
    #pragma unroll
    for (int kk=0;kk<2;++kk){
      s16x8 ap[3];
      #pragma unroll
      for (int m=0;m<3;++m)
        ap[m] = *(const s16x8*)&p_lds[(m*16+fr)*72 + kk*32 + fq*8];
      #pragma unroll
      for (int n=0;n<4;++n){
        s16x8 bv;
        #pragma unroll
        for (int i2=0;i2<8;++i2)
          bv[i2] = (short)v_lds[(kk*32 + fq*8 + i2)*72 + n*16 + fr];
        #pragma unroll
        for (int m=0;m<3;++m)
          acc_o[m][n] = __builtin_amdgcn_mfma_f32_16x16x32_bf16(ap[m], bv, acc_o[m][n], 0,0,0);
      }
    }
  }
  size_t pbase = ((size_t)(bh*NSP + sp))*48*64;
  #pragma unroll
  for (int m=0;m<3;++m)
    #pragma unroll
    for (int n=0;n<4;++n)
      #pragma unroll
      for (int i=0;i<4;++i){
        int qi = m*16 + fq*4 + i, d = n*16 + fr;
        part_ctx[pbase + (size_t)qi*64 + d] = acc_o[m][n][i];
      }
  if (fr==0){
    #pragma unroll
    for (int m=0;m<3;++m)
      #pragma unroll
      for (int i=0;i<4;++i){
        int qi = m*16 + fq*4 + i;
        part_ml[((size_t)(bh*NSP+sp))*96 + qi*2+0] = m_run[m][i];
        part_ml[((size_t)(bh*NSP+sp))*96 + qi*2+1] = l_run[m][i];
      }
  }
}

// ---------------- combine NSP partials per (bh, qi), write bf16 ctx (zero-pad qi>=41) ----------------
__global__ __launch_bounds__(64) void k_combine(const float* __restrict__ part_ctx, const float* __restrict__ part_ml,
                                                u16* __restrict__ ctxb, int NSP){
  int bh = blockIdx.x, qi = blockIdx.y;
  int b = bh>>4, h = bh&15;
  int lane = threadIdx.x;
  size_t dst = ((size_t)(b*48+qi))*1024 + h*64 + lane;
  if (qi >= 41){ ctxb[dst] = 0; return; }
  float M = -3e38f;
  for (int p=0;p<NSP;++p)
    M = fmaxf(M, part_ml[((size_t)(bh*NSP+p))*96 + qi*2+0]);
  float l = 0.f, c = 0.f;
  for (int p=0;p<NSP;++p){
    float pm = part_ml[((size_t)(bh*NSP+p))*96 + qi*2+0];
    float pl = part_ml[((size_t)(bh*NSP+p))*96 + qi*2+1];
    float w = __expf(pm-M);
    l += pl*w;
    c += w * part_ctx[((size_t)(bh*NSP+p))*48*64 + (size_t)qi*64 + lane];
  }
  ctxb[dst] = f2bf(c / l);
}

// ---------------- finalize: selected rows = oacc + out_b (f32), others = per-batch mean ----------------
__global__ __launch_bounds__(256) void k_finalize(const float* __restrict__ oacc, const float* __restrict__ outb,
                                                  const float* __restrict__ colsum,
                                                  const int* __restrict__ sel, float* __restrict__ out){
  int row = blockIdx.x;
  int b = row >> 12;
  int t = threadIdx.x;
  int s = sel[row];
  float4 o;
  if (s >= 0){
    float4 a = *(const float4*)(oacc + ((size_t)(b*48+s))*1024 + t*4);
    float4 bb = *(const float4*)(outb + t*4);
    o.x = a.x+bb.x; o.y = a.y+bb.y; o.z = a.z+bb.z; o.w = a.w+bb.w;
  } else {
    o = *(const float4*)(colsum + b*1024 + t*4);
    o.x *= (1.f/4096.f); o.y *= (1.f/4096.f); o.z *= (1.f/4096.f); o.w *= (1.f/4096.f);
  }
  *(float4*)(out + (size_t)row*1024 + t*4) = o;
}

extern "C" void kernel_launch(void* const* d_in, const int* in_sizes, int n_in,
                              void* d_out, int out_size, void* d_ws, size_t ws_size,
                              hipStream_t stream) {
  const float* x    = (const float*)d_in[0];
  const float* ipw  = (const float*)d_in[1];
  const float* ipb  = (const float*)d_in[2];
  const float* outw = (const float*)d_in[3];
  const float* outb = (const float*)d_in[4];
  float* out = (float*)d_out;
  char* ws = (char*)d_ws;

  // ---- ws-adaptive config: G heads per KV chunk, NSP key-splits for attention ----
  const int cfgG[7]   = {16, 8, 4, 2, 1, 1, 1};
  const int cfgNSP[7] = {16,16,16,16,16, 4, 2};
  int G = 1, NSP = 2;
  size_t oXB=0,oWIP=0,oBIP=0,oWO=0,oEN=0,oCS=0,oQA=0,oOA=0,oTK=0,oSEL=0,oAQ=0,oCTXB=0,oPML=0,oPCTX=0,oKV=0;
  for (int ci=0; ci<7; ++ci){
    int g = cfgG[ci], nsp = cfgNSP[ci];
    size_t o = 0;
    size_t xb=o;   o += 67108864;            // xb    bf16[32768][1024]
    size_t wip=o;  o += 6291456;             // ipwb  bf16[3072][1024]
    size_t bip=o;  o += 6144;                // ipbb  bf16[3072]
    size_t wo=o;   o += 2097152;             // outwb bf16[1024][1024]
    size_t en=o;   o += 131072;              // energy f32[32768]
    size_t cs=o;   o += 32768;               // colsum f32[8*1024], contiguous with qacc+oacc for one memset
    size_t qa=o;   o += 1572864;             // qacc  f32[384][1024]
    size_t oa=o;   o += 1572864;             // oacc  f32[384][1024]
    size_t tk=o;   o += 2048;                // topk  int[8*64]
    size_t sl=o;   o += 131072;              // sel   int[32768]
    size_t aq=o;   o += 786432;              // Aq    bf16[384][1024]
    size_t cb=o;   o += 786432;              // ctxb  bf16[384][1024]
    size_t pm=o;   o += (size_t)nsp*49152;   // pml   f32[128*nsp*96]
    size_t pc=o;   o += (size_t)nsp*1572864; // pctx  f32[128*nsp*48*64]
    size_t kv=o;   o += (size_t)g*8388608;   // KV    bf16[32768][g*128]
    if (o <= ws_size || ci == 6){
      G=g; NSP=nsp;
      oXB=xb; oWIP=wip; oBIP=bip; oWO=wo; oEN=en; oCS=cs; oQA=qa; oOA=oa; oTK=tk; oSEL=sl;
      oAQ=aq; oCTXB=cb; oPML=pm; oPCTX=pc; oKV=kv;
      break;
    }
  }

  u16*   xb     = (u16*)(ws + oXB);
  u16*   ipwb   = (u16*)(ws + oWIP);
  u16*   ipbb   = (u16*)(ws + oBIP);
  u16*   outwb  = (u16*)(ws + oWO);
  float* energy = (float*)(ws + oEN);
  float* colsum = (float*)(ws + oCS);
  float* qacc   = (float*)(ws + oQA);
  float* oacc   = (float*)(ws + oOA);
  int*   topk   = (int*)(ws + oTK);
  int*   sel    = (int*)(ws + oSEL);
  u16*   Aq     = (u16*)(ws + oAQ);
  u16*   ctxb   = (u16*)(ws + oCTXB);
  float* pml    = (float*)(ws + oPML);
  float* pctx   = (float*)(ws + oPCTX);
  u16*   KV     = (u16*)(ws + oKV);

  hipMemsetAsync(colsum, 0, 32768 + 2*1572864, stream);

  k_prep_all <<<12291, 256, 0, stream>>>(x, xb, energy, ipw, ipb, outw, ipwb, ipbb, outwb);
  k_stats  <<<264, 256, 0, stream>>>(xb, colsum, energy, topk, sel);
  k_gather_q<<<dim3(8,48), 256, 0, stream>>>(x, topk, Aq);

  // Q = Aq @ Wq^T   split-K f32 accum; bias+scale folded into k_attn's fragment build
  k_gemm_sk <<<dim3(24,8), 256, 0, stream>>>(Aq, ipwb, qacc);

  if (G == 16){
    const int nt = 64/NSP;
    k_kvgemm6 <<<1024, 512, 0, stream>>>(xb,
        ipwb + (size_t)1024*1024, ipwb + (size_t)2048*1024,
        ipbb + 1024, ipbb + 2048, KV);
    k_attn <<<dim3(128, NSP), 64, 0, stream>>>(qacc, ipb, KV, pctx, pml, 16, 0, 2048, 1024, nt, NSP);
  } else {
    const int nchunk = 16 / G;
    const int ncols = G*128, half = G*64, nt = 64/NSP;
    for (int c=0; c<nchunk; ++c){
      int hg0 = c*G;
      k_gemm <<<G*256, 256, 0, stream>>>(
          xb,
          ipwb + (size_t)(1024 + hg0*64)*1024,
          ipwb + (size_t)(2048 + hg0*64)*1024,
          ipbb + 1024 + hg0*64,
          ipbb + 2048 + hg0*64,
          KV, G, ncols, half, 1.0f);
      k_attn <<<dim3(8*G, NSP), 64, 0, stream>>>(qacc, ipb, KV, pctx, pml, G, hg0, ncols, half, nt, NSP);
    }
  }

  k_combine<<<dim3(128,48), 64, 0, stream>>>(pctx, pml, ctxb, NSP);

  // out_sel = ctx @ Wo^T   split-K f32 accum, bias at finalize
  k_gemm_sk <<<dim3(24,8), 256, 0, stream>>>(ctxb, outwb, oacc);

  k_finalize<<<32768, 256, 0, stream>>>(oacc, outb, colsum, sel, out);
}

// Round 15
// 370.550 us; speedup vs baseline: 7.2890x; 1.0028x over previous
//
#include <hip/hip_runtime.h>

using u16 = unsigned short;
using u32 = unsigned int;
using u64 = unsigned long long;
typedef __attribute__((ext_vector_type(8))) short s16x8;
typedef __attribute__((ext_vector_type(4))) short s16x4;
typedef __attribute__((ext_vector_type(4))) float f32x4;

__device__ __forceinline__ float bf2f(u16 u){ return __uint_as_float(((u32)u)<<16); }
__device__ __forceinline__ u16 f2bf(float f){
  u32 u = __float_as_uint(f);
  u += 0x7fffu + ((u>>16)&1u);
  return (u16)(u>>16);
}
__device__ __forceinline__ void gl_lds16(const void* g, void* l){
  __builtin_amdgcn_global_load_lds((const __attribute__((address_space(1))) void*)g,
                                   (__attribute__((address_space(3))) void*)l, 16, 0, 0);
}

// ---------------- fused: x fp32->bf16 + energy (blocks 0..8191) | weight cvt (blocks 8192..12290) ----------------
__global__ __launch_bounds__(256) void k_prep_all(const float* __restrict__ x, u16* __restrict__ xb,
                                                  float* __restrict__ energy,
                                                  const float* __restrict__ ipw, const float* __restrict__ ipb,
                                                  const float* __restrict__ outw,
                                                  u16* __restrict__ ipwb, u16* __restrict__ ipbb,
                                                  u16* __restrict__ outwb){
  int bid = blockIdx.x;
  if (bid < 8192){
    int tok = bid*4 + (threadIdx.x>>6);
    int lane = threadIdx.x & 63;
    const float* p = x + (size_t)tok*1024 + lane*16;
    float4 a[4];
    #pragma unroll
    for (int j=0;j<4;++j) a[j] = ((const float4*)p)[j];
    float s = 0.f;
    s16x8 o0, o1;
    #pragma unroll
    for (int j=0;j<2;++j){
      o0[j*4+0]=(short)f2bf(a[j].x); o0[j*4+1]=(short)f2bf(a[j].y);
      o0[j*4+2]=(short)f2bf(a[j].z); o0[j*4+3]=(short)f2bf(a[j].w);
    }
    #pragma unroll
    for (int j=0;j<2;++j){
      o1[j*4+0]=(short)f2bf(a[2+j].x); o1[j*4+1]=(short)f2bf(a[2+j].y);
      o1[j*4+2]=(short)f2bf(a[2+j].z); o1[j*4+3]=(short)f2bf(a[2+j].w);
    }
    #pragma unroll
    for (int j=0;j<4;++j){
      s += a[j].x*a[j].x + a[j].y*a[j].y + a[j].z*a[j].z + a[j].w*a[j].w;
    }
    u16* xo = xb + (size_t)tok*1024 + lane*16;
    *(s16x8*)xo = o0;
    *(s16x8*)(xo+8) = o1;
    #pragma unroll
    for (int off=32; off; off>>=1) s += __shfl_xor(s, off);
    if (lane==0) energy[tok] = s;
    return;
  }
  int b2 = bid - 8192;
  const float* src; u16* dst; int n; int base;
  if (b2 < 3072){ src=ipw; dst=ipwb; n=3145728; base=b2; }
  else if (b2 < 3075){ src=ipb; dst=ipbb; n=3072; base=b2-3072; }
  else { src=outw; dst=outwb; n=1048576; base=b2-3075; }
  int i = (base*256 + threadIdx.x)*4;
  if (i >= n) return;
  float4 v = *(const float4*)(src + i);
  s16x4 o;
  o[0]=(short)f2bf(v.x); o[1]=(short)f2bf(v.y); o[2]=(short)f2bf(v.z); o[3]=(short)f2bf(v.w);
  *(s16x4*)(dst + i) = o;
}

// ---------------- fused stats: colsum (blocks 0..255) + top-41 (blocks 256..263, 1 barrier/iter) ----------------
__global__ __launch_bounds__(256) void k_stats(const u16* __restrict__ xb, float* __restrict__ colsum,
                                               const float* __restrict__ energy, int* __restrict__ topk,
                                               int* __restrict__ sel){
  if (blockIdx.x < 256){
    int b = blockIdx.x >> 5, sc = blockIdx.x & 31;
    int t = threadIdx.x;
    float acc[4] = {0.f,0.f,0.f,0.f};
    for (int s = sc*128; s < sc*128+128; ++s){
      s16x4 v = *(const s16x4*)(xb + ((size_t)b*4096 + s)*1024 + t*4);
      #pragma unroll
      for (int i=0;i<4;++i) acc[i] += bf2f((u16)v[i]);
    }
    #pragma unroll
    for (int i=0;i<4;++i) atomicAdd(&colsum[b*1024 + t*4 + i], acc[i]);
    return;
  }
  int b = blockIdx.x - 256;
  int t = threadIdx.x;
  int lane = t & 63, wid = t >> 6;
  __shared__ u64 wmax[2][4];
  u64 v[16];
  #pragma unroll
  for (int i=0;i<16;++i){
    u32 tok = i*256 + t;
    float e = energy[b*4096 + tok];
    v[i] = ((u64)__float_as_uint(e) << 32) | (u32)(~tok);
    sel[b*4096 + tok] = -1;
  }
  __syncthreads();
  for (int it=0; it<41; ++it){
    u64 m = v[0];
    #pragma unroll
    for (int i=1;i<16;++i) m = v[i] > m ? v[i] : m;
    #pragma unroll
    for (int off=32; off; off>>=1){
      u64 o = __shfl_xor(m, off);
      m = o > m ? o : m;
    }
    if (lane==0) wmax[it&1][wid] = m;
    __syncthreads();
    u64 g = wmax[it&1][0];
    #pragma unroll
    for (int w=1;w<4;++w) g = wmax[it&1][w] > g ? wmax[it&1][w] : g;
    u32 tok = (~(u32)g) & 4095u;
    if (t==0){ topk[b*64+it] = (int)tok; sel[b*4096 + tok] = it; }
    #pragma unroll
    for (int i=0;i<16;++i){
      if ((u32)(i*256 + t) == tok) v[i] = 0;
    }
  }
}

// ---------------- gather selected x rows -> Aq bf16 [8*48][1024], zero-pad qi>=41 ----------------
__global__ __launch_bounds__(256) void k_gather_q(const float* __restrict__ x, const int* __restrict__ topk,
                                                  u16* __restrict__ Aq){
  int b = blockIdx.x, qi = blockIdx.y, t = threadIdx.x;
  size_t dst = ((size_t)(b*48+qi))*1024 + t*4;
  if (qi >= 41){ s16x4 z = {0,0,0,0}; *(s16x4*)&Aq[dst] = z; return; }
  int tok = topk[b*64+qi];
  float4 v = *(const float4*)(x + ((size_t)b*4096 + tok)*1024 + t*4);
  s16x4 o;
  o[0]=(short)f2bf(v.x); o[1]=(short)f2bf(v.y); o[2]=(short)f2bf(v.z); o[3]=(short)f2bf(v.w);
  *(s16x4*)&Aq[dst] = o;
}

// ---------------- generalized bf16 GEMM (m97 structure), kept for small-ws fallback KV path ----------------
__global__ __launch_bounds__(256) void k_gemm(const u16* __restrict__ A, const u16* __restrict__ Bk,
                                              const u16* __restrict__ Bv,
                                              const u16* __restrict__ biask, const u16* __restrict__ biasv,
                                              u16* __restrict__ C, int nbn, int ncols, int half, float cscale){
  __shared__ u16 As[128*64];
  __shared__ u16 Bs[128*64];
  const int tid = threadIdx.x;
  const int bn = blockIdx.x % nbn;
  const int bm = blockIdx.x / nbn;
  const int m0 = bm*128, n0 = bn*128;
  const u16* Bbase  = (n0 < half) ? (Bk + (size_t)n0*1024) : (Bv + (size_t)(n0-half)*1024);
  const u16* biasp  = (n0 < half) ? (biask + n0) : (biasv + (n0-half));
  const int lane = tid & 63;
  const int wave = tid >> 6;
  const int wr = wave >> 1, wc = wave & 1;
  const int fr = lane & 15;
  const int fq = lane >> 4;
  f32x4 acc[4][4] = {};
  for (int k0 = 0; k0 < 1024; k0 += 64){
    __syncthreads();
    #pragma unroll
    for (int j=0;j<4;++j){
      int idx = j*256 + tid;
      int r = idx>>3; int cc = (idx&7)*8;
      gl_lds16(A + (size_t)(m0+r)*1024 + k0 + cc, &As[r*64+cc]);
    }
    #pragma unroll
    for (int j=0;j<4;++j){
      int idx = j*256 + tid;
      int r = idx>>3; int cc = (idx&7)*8;
      gl_lds16(Bbase + (size_t)r*1024 + k0 + cc, &Bs[r*64+cc]);
    }
    __syncthreads();
    #pragma unroll
    for (int kk=0; kk<64; kk+=32){
      s16x8 af[4], bfv[4];
      #pragma unroll
      for (int m=0;m<4;++m) af[m] = *(const s16x8*)&As[(wr*64 + m*16 + fr)*64 + kk + fq*8];
      #pragma unroll
      for (int n=0;n<4;++n) bfv[n] = *(const s16x8*)&Bs[(wc*64 + n*16 + fr)*64 + kk + fq*8];
      #pragma unroll
      for (int m=0;m<4;++m)
        #pragma unroll
        for (int n=0;n<4;++n)
          acc[m][n] = __builtin_amdgcn_mfma_f32_16x16x32_bf16(af[m], bfv[n], acc[m][n], 0,0,0);
    }
  }
  #pragma unroll
  for (int n=0;n<4;++n){
    int cl = wc*64 + n*16 + fr;
    int col = n0 + cl;
    float bvv = bf2f(biasp[cl]);
    #pragma unroll
    for (int m=0;m<4;++m){
      int rowb = m0 + wr*64 + m*16 + fq*4;
      f32x4 v = acc[m][n];
      #pragma unroll
      for (int i=0;i<4;++i)
        C[(size_t)(rowb+i)*ncols + col] = f2bf((v[i]+bvv)*cscale);
    }
  }
}

// ---------------- split-K small GEMM: grid (24, 8), K=128/chunk; f32 atomicAdd accum (no bias) ----------------
__global__ __launch_bounds__(256) void k_gemm_sk(const u16* __restrict__ A, const u16* __restrict__ B,
                                                 float* __restrict__ Cacc){
  __shared__ u16 As[128*64];
  __shared__ u16 Bs[128*64];
  const int tid = threadIdx.x;
  const int bn = blockIdx.x & 7;
  const int bm = blockIdx.x >> 3;
  const int kc = blockIdx.y;
  const int m0 = bm*128, n0 = bn*128;
  const u16* Bbase = B + (size_t)n0*1024;
  const int lane = tid & 63;
  const int wave = tid >> 6;
  const int wr = wave >> 1, wc = wave & 1;
  const int fr = lane & 15;
  const int fq = lane >> 4;
  f32x4 acc[4][4] = {};
  for (int k0 = kc*128; k0 < kc*128+128; k0 += 64){
    __syncthreads();
    #pragma unroll
    for (int j=0;j<4;++j){
      int idx = j*256 + tid;
      int r = idx>>3; int cc = (idx&7)*8;
      gl_lds16(A + (size_t)(m0+r)*1024 + k0 + cc, &As[r*64+cc]);
    }
    #pragma unroll
    for (int j=0;j<4;++j){
      int idx = j*256 + tid;
      int r = idx>>3; int cc = (idx&7)*8;
      gl_lds16(Bbase + (size_t)r*1024 + k0 + cc, &Bs[r*64+cc]);
    }
    __syncthreads();
    #pragma unroll
    for (int kk=0; kk<64; kk+=32){
      s16x8 af[4], bfv[4];
      #pragma unroll
      for (int m=0;m<4;++m) af[m] = *(const s16x8*)&As[(wr*64 + m*16 + fr)*64 + kk + fq*8];
      #pragma unroll
      for (int n=0;n<4;++n) bfv[n] = *(const s16x8*)&Bs[(wc*64 + n*16 + fr)*64 + kk + fq*8];
      #pragma unroll
      for (int m=0;m<4;++m)
        #pragma unroll
        for (int n=0;n<4;++n)
          acc[m][n] = __builtin_amdgcn_mfma_f32_16x16x32_bf16(af[m], bfv[n], acc[m][n], 0,0,0);
    }
  }
  #pragma unroll
  for (int n=0;n<4;++n){
    int col = n0 + wc*64 + n*16 + fr;
    #pragma unroll
    for (int m=0;m<4;++m){
      int rowb = m0 + wr*64 + m*16 + fq*4;
      f32x4 v = acc[m][n];
      #pragma unroll
      for (int i=0;i<4;++i)
        atomicAdd(&Cacc[(size_t)(rowb+i)*1024 + col], v[i]);
    }
  }
}

// ================= KV GEMM v6c: 2-slot LDS (64 KiB) -> 2 blocks/CU; vmcnt FIXED (4 loads/tile, not 8) =================
// Round-13 race: stage = 4 gl_lds/tile, so after issuing T+2 the counter is 8 -> vmcnt(8) waited for NOTHING
// and frag reads raced T+1's in-flight loads. Correct counts: steady vmcnt(4), tail vmcnt(0), prologue vmcnt(4).
__device__ __forceinline__ void stageA4(const u16* __restrict__ A, int m0, int k0, u16* slot, int tid){
  #pragma unroll
  for (int j=0;j<2;++j){
    int idx = j*512 + tid;
    int row = idx>>2;
    int sc = (idx&3) ^ ((row>>1)&3);
    gl_lds16(A + (size_t)(m0+row)*1024 + k0 + sc*8, slot + (size_t)idx*8);
  }
}
__device__ __forceinline__ void stageB4(const u16* __restrict__ B, int k0, u16* slot, int tid){
  #pragma unroll
  for (int j=0;j<2;++j){
    int idx = j*512 + tid;
    int row = idx>>2;
    int sc = (idx&3) ^ ((row>>1)&3);
    gl_lds16(B + (size_t)row*1024 + k0 + sc*8, slot + 8192 + (size_t)idx*8);
  }
}
__device__ __forceinline__ s16x8 fragA4(const u16* slot, int row, int fq){
  int pc = fq ^ ((row>>1)&3);
  return *(const s16x8*)(slot + row*32 + pc*8);
}
__device__ __forceinline__ s16x8 fragB4(const u16* slot, int row, int fq){
  int pc = fq ^ ((row>>1)&3);
  return *(const s16x8*)(slot + 8192 + row*32 + pc*8);
}

#define KSTEP6(T, CA, CB, NA, NB)                                              \
  asm volatile("s_waitcnt lgkmcnt(0)" ::: "memory");                           \
  __builtin_amdgcn_sched_barrier(0);                                           \
  __builtin_amdgcn_s_barrier();                                                \
  __builtin_amdgcn_sched_barrier(0);                                           \
  if ((T) < 30){                                                               \
    u16* ns = lds + ((T)&1)*16384;                                             \
    stageA4(A, m0, ((T)+2)*32, ns, tid);                                       \
    stageB4(Bbase, ((T)+2)*32, ns, tid);                                       \
  }                                                                            \
  if ((T) < 30)      { asm volatile("s_waitcnt vmcnt(4)" ::: "memory"); }      \
  else if ((T)==30)  { asm volatile("s_waitcnt vmcnt(0)" ::: "memory"); }      \
  __builtin_amdgcn_sched_barrier(0);                                           \
  __builtin_amdgcn_s_barrier();                                                \
  __builtin_amdgcn_sched_barrier(0);                                           \
  if ((T) < 31){                                                               \
    const u16* rs = lds + (((T)+1)&1)*16384;                                   \
    _Pragma("unroll")                                                          \
    for (int m=0;m<8;++m) NA[m] = fragA4(rs, wm*128 + m*16 + fr, fq);          \
    _Pragma("unroll")                                                          \
    for (int n=0;n<4;++n) NB[n] = fragB4(rs, wn*64 + n*16 + fr, fq);           \
  }                                                                            \
  __builtin_amdgcn_sched_barrier(0);                                           \
  __builtin_amdgcn_s_setprio(1);                                               \
  _Pragma("unroll")                                                            \
  for (int m=0;m<8;++m)                                                        \
    _Pragma("unroll")                                                          \
    for (int n=0;n<4;++n)                                                      \
      acc[m][n] = __builtin_amdgcn_mfma_f32_16x16x32_bf16(CA[m], CB[n], acc[m][n], 0,0,0); \
  __builtin_amdgcn_s_setprio(0);

__global__ __launch_bounds__(512) void k_kvgemm6(const u16* __restrict__ A, const u16* __restrict__ Bk,
                                                 const u16* __restrict__ Bv,
                                                 const u16* __restrict__ biask, const u16* __restrict__ biasv,
                                                 u16* __restrict__ C){
  __shared__ u16 lds[2*16384];   // 64 KiB -> 2 blocks/CU (LDS-limited), VGPR free (~128)
  const int tid = threadIdx.x;
  const int sbid = ((int)blockIdx.x & 7)*128 + ((int)blockIdx.x >> 3);   // T1 XCD swizzle, 1024%8==0
  const int bn = sbid & 7;
  const int bm = sbid >> 3;
  const int m0 = bm*256, n0 = bn*256;
  const u16* Bbase = (bn < 4) ? (Bk + (size_t)n0*1024) : (Bv + (size_t)(n0-1024)*1024);
  const u16* biasp = (bn < 4) ? (biask + n0) : (biasv + (n0-1024));
  const int lane = tid & 63, wid = tid >> 6;
  const int wm = wid >> 2, wn = wid & 3;
  const int fr = lane & 15, fq = lane >> 4;
  f32x4 acc[8][4] = {};
  s16x8 afr0[8], bfr0[4], afr1[8], bfr1[4];

  // prologue: tiles 0,1 -> slots 0,1 (4 loads each); vmcnt(4) retires tile 0's 4; read frags(0)
  stageA4(A, m0, 0, lds, tid);          stageB4(Bbase, 0, lds, tid);
  stageA4(A, m0, 32, lds+16384, tid);   stageB4(Bbase, 32, lds+16384, tid);
  asm volatile("s_waitcnt vmcnt(4)" ::: "memory");
  __builtin_amdgcn_sched_barrier(0);
  __builtin_amdgcn_s_barrier();
  __builtin_amdgcn_sched_barrier(0);
  #pragma unroll
  for (int m=0;m<8;++m) afr0[m] = fragA4(lds, wm*128 + m*16 + fr, fq);
  #pragma unroll
  for (int n=0;n<4;++n) bfr0[n] = fragB4(lds, wn*64 + n*16 + fr, fq);

  for (int t=0; t<32; t+=2){
    KSTEP6(t,   afr0, bfr0, afr1, bfr1);
    KSTEP6(t+1, afr1, bfr1, afr0, bfr0);
  }

  // ---- epilogue: bias + bf16 -> LDS (64 KiB = one 128-row half), coalesced 16B stores ----
  u16* eLDS = lds;
  #pragma unroll
  for (int h=0; h<2; ++h){
    __syncthreads();
    if (wm == h){
      #pragma unroll
      for (int n=0;n<4;++n){
        int cl = wn*64 + n*16 + fr;
        float bvv = bf2f(biasp[cl]);
        #pragma unroll
        for (int m=0;m<8;++m){
          #pragma unroll
          for (int i=0;i<4;++i){
            int r = m*16 + fq*4 + i;
            eLDS[r*256 + cl] = f2bf(acc[m][n][i] + bvv);
          }
        }
      }
    }
    __syncthreads();
    #pragma unroll
    for (int j=0;j<8;++j){
      int e = j*512 + tid;
      int row = e >> 5, ch = e & 31;
      *(s16x8*)(C + (size_t)(m0 + h*128 + row)*2048 + n0 + ch*8) = *(const s16x8*)&eLDS[row*256 + ch*8];
    }
  }
}

// ---------------- flash attention: Q built from qacc f32 + bias + scale in-register ----------------
__global__ __launch_bounds__(64) void k_attn(const float* __restrict__ qacc, const float* __restrict__ bq,
                                             const u16* __restrict__ KV,
                                             float* __restrict__ part_ctx, float* __restrict__ part_ml,
                                             int G, int hg0, int ncols, int half, int nt, int NSP){
  const int b = blockIdx.x / G, hl = blockIdx.x % G;
  const int h = hg0 + hl;
  const int bh = b*16 + h;
  const int sp = blockIdx.y;
  const int lane = threadIdx.x;
  const int fr = lane & 15, fq = lane >> 4;
  __shared__ u16 k_lds[64*72];
  __shared__ u16 v_lds[64*72];
  __shared__ u16 p_lds[48*72];
  s16x8 af[3][2];
  #pragma unroll
  for (int m=0;m<3;++m)
    #pragma unroll
    for (int kk=0;kk<2;++kk){
      const float* qa = qacc + ((size_t)(b*48 + m*16 + fr))*1024 + h*64 + kk*32 + fq*8;
      const float* bp = bq + h*64 + kk*32 + fq*8;
      s16x8 f;
      #pragma unroll
      for (int j=0;j<8;++j) f[j] = (short)f2bf((qa[j] + bp[j])*0.125f);
      af[m][kk] = f;
    }
  f32x4 acc_o[3][4] = {};
  float m_run[3][4], l_run[3][4];
  #pragma unroll
  for (int m=0;m<3;++m)
    #pragma unroll
    for (int i=0;i<4;++i){ m_run[m][i] = -3e38f; l_run[m][i] = 0.f; }

  for (int it=0; it<nt; ++it){
    int s0 = (sp*nt + it)*64;
    __syncthreads();
    #pragma unroll
    for (int j=0;j<8;++j){
      int r = j*8 + (lane>>3);
      int sg = (lane&7)*8;
      const u16* kp = KV + ((size_t)(b*4096 + s0 + r))*ncols + hl*64 + sg;
      *(s16x8*)&k_lds[r*72+sg] = *(const s16x8*)kp;
      *(s16x8*)&v_lds[r*72+sg] = *(const s16x8*)(kp+half);
    }
    __syncthreads();
    f32x4 sc4[3][4] = {};
    #pragma unroll
    for (int kk=0;kk<2;++kk){
      s16x8 bk[4];
      #pragma unroll
      for (int n=0;n<4;++n)
        bk[n] = *(const s16x8*)&k_lds[(n*16+fr)*72 + kk*32 + fq*8];
      #pragma unroll
      for (int m=0;m<3;++m)
        #pragma unroll
        for (int n=0;n<4;++n)
          sc4[m][n] = __builtin_amdgcn_mfma_f32_16x16x32_bf16(af[m][kk], bk[n], sc4[m][n], 0,0,0);
    }
    #pragma unroll
    for (int m=0;m<3;++m){
      #pragma unroll
      for (int i=0;i<4;++i){
        float rmax = fmaxf(fmaxf(sc4[m][0][i], sc4[m][1][i]), fmaxf(sc4[m][2][i], sc4[m][3][i]));
        #pragma unroll
        for (int off=1; off<16; off<<=1) rmax = fmaxf(rmax, __shfl_xor(rmax, off));
        float mnew = fmaxf(m_run[m][i], rmax);
        float alpha = __expf(m_run[m][i] - mnew);
        m_run[m][i] = mnew;
        float rsum = 0.f;
        #pragma unroll
        for (int n=0;n<4;++n){
          float p = __expf(sc4[m][n][i] - mnew);
          rsum += p;
          p_lds[(m*16 + fq*4 + i)*72 + n*16 + fr] = f2bf(p);
        }
        #pragma unroll
        for (int off=1; off<16; off<<=1) rsum += __shfl_xor(rsum, off);
        l_run[m][i] = l_run[m][i]*alpha + rsum;
        #pragma unroll
        for (int n=0;n<4;++n) acc_o[m][n][i] *= alpha;
      }
    }
    __syncthreads();
    #pragma unroll
    for (int kk=0;kk<2;++kk){
      s16x8 ap[3];
      #pragma unroll
      for (int m=0;m<3;++m)
        ap[m] = *(const s16x8*)&p_lds[(m*16+fr)*72 + kk*32 + fq*8];
      #pragma unroll
      for (int n=0;n<4;++n){
        s16x8 bv;
        #pragma unroll
        for (int i2=0;i2<8;++i2)
          bv[i2] = (short)v_lds[(kk*32 + fq*8 + i2)*72 + n*16 + fr];
        #pragma unroll
        for (int m=0;m<3;++m)
          acc_o[m][n] = __builtin_amdgcn_mfma_f32_16x16x32_bf16(ap[m], bv, acc_o[m][n], 0,0,0);
      }
    }
  }
  size_t pbase = ((size_t)(bh*NSP + sp))*48*64;
  #pragma unroll
  for (int m=0;m<3;++m)
    #pragma unroll
    for (int n=0;n<4;++n)
      #pragma unroll
      for (int i=0;i<4;++i){
        int qi = m*16 + fq*4 + i, d = n*16 + fr;
        part_ctx[pbase + (size_t)qi*64 + d] = acc_o[m][n][i];
      }
  if (fr==0){
    #pragma unroll
    for (int m=0;m<3;++m)
      #pragma unroll
      for (int i=0;i<4;++i){
        int qi = m*16 + fq*4 + i;
        part_ml[((size_t)(bh*NSP+sp))*96 + qi*2+0] = m_run[m][i];
        part_ml[((size_t)(bh*NSP+sp))*96 + qi*2+1] = l_run[m][i];
      }
  }
}

// ---------------- combine NSP partials per (bh, qi), write bf16 ctx (zero-pad qi>=41) ----------------
__global__ __launch_bounds__(64) void k_combine(const float* __restrict__ part_ctx, const float* __restrict__ part_ml,
                                                u16* __restrict__ ctxb, int NSP){
  int bh = blockIdx.x, qi = blockIdx.y;
  int b = bh>>4, h = bh&15;
  int lane = threadIdx.x;
  size_t dst = ((size_t)(b*48+qi))*1024 + h*64 + lane;
  if (qi >= 41){ ctxb[dst] = 0; return; }
  float M = -3e38f;
  for (int p=0;p<NSP;++p)
    M = fmaxf(M, part_ml[((size_t)(bh*NSP+p))*96 + qi*2+0]);
  float l = 0.f, c = 0.f;
  for (int p=0;p<NSP;++p){
    float pm = part_ml[((size_t)(bh*NSP+p))*96 + qi*2+0];
    float pl = part_ml[((size_t)(bh*NSP+p))*96 + qi*2+1];
    float w = __expf(pm-M);
    l += pl*w;
    c += w * part_ctx[((size_t)(bh*NSP+p))*48*64 + (size_t)qi*64 + lane];
  }
  ctxb[dst] = f2bf(c / l);
}

// ---------------- finalize: selected rows = oacc + out_b (f32), others = per-batch mean ----------------
__global__ __launch_bounds__(256) void k_finalize(const float* __restrict__ oacc, const float* __restrict__ outb,
                                                  const float* __restrict__ colsum,
                                                  const int* __restrict__ sel, float* __restrict__ out){
  int row = blockIdx.x;
  int b = row >> 12;
  int t = threadIdx.x;
  int s = sel[row];
  float4 o;
  if (s >= 0){
    float4 a = *(const float4*)(oacc + ((size_t)(b*48+s))*1024 + t*4);
    float4 bb = *(const float4*)(outb + t*4);
    o.x = a.x+bb.x; o.y = a.y+bb.y; o.z = a.z+bb.z; o.w = a.w+bb.w;
  } else {
    o = *(const float4*)(colsum + b*1024 + t*4);
    o.x *= (1.f/4096.f); o.y *= (1.f/4096.f); o.z *= (1.f/4096.f); o.w *= (1.f/4096.f);
  }
  *(float4*)(out + (size_t)row*1024 + t*4) = o;
}

extern "C" void kernel_launch(void* const* d_in, const int* in_sizes, int n_in,
                              void* d_out, int out_size, void* d_ws, size_t ws_size,
                              hipStream_t stream) {
  const float* x    = (const float*)d_in[0];
  const float* ipw  = (const float*)d_in[1];
  const float* ipb  = (const float*)d_in[2];
  const float* outw = (const float*)d_in[3];
  const float* outb = (const float*)d_in[4];
  float* out = (float*)d_out;
  char* ws = (char*)d_ws;

  // ---- ws-adaptive config: G heads per KV chunk, NSP key-splits for attention ----
  const int cfgG[7]   = {16, 8, 4, 2, 1, 1, 1};
  const int cfgNSP[7] = {16,16,16,16,16, 4, 2};
  int G = 1, NSP = 2;
  size_t oXB=0,oWIP=0,oBIP=0,oWO=0,oEN=0,oCS=0,oQA=0,oOA=0,oTK=0,oSEL=0,oAQ=0,oCTXB=0,oPML=0,oPCTX=0,oKV=0;
  for (int ci=0; ci<7; ++ci){
    int g = cfgG[ci], nsp = cfgNSP[ci];
    size_t o = 0;
    size_t xb=o;   o += 67108864;            // xb    bf16[32768][1024]
    size_t wip=o;  o += 6291456;             // ipwb  bf16[3072][1024]
    size_t bip=o;  o += 6144;                // ipbb  bf16[3072]
    size_t wo=o;   o += 2097152;             // outwb bf16[1024][1024]
    size_t en=o;   o += 131072;              // energy f32[32768]
    size_t cs=o;   o += 32768;               // colsum f32[8*1024], contiguous with qacc+oacc for one memset
    size_t qa=o;   o += 1572864;             // qacc  f32[384][1024]
    size_t oa=o;   o += 1572864;             // oacc  f32[384][1024]
    size_t tk=o;   o += 2048;                // topk  int[8*64]
    size_t sl=o;   o += 131072;              // sel   int[32768]
    size_t aq=o;   o += 786432;              // Aq    bf16[384][1024]
    size_t cb=o;   o += 786432;              // ctxb  bf16[384][1024]
    size_t pm=o;   o += (size_t)nsp*49152;   // pml   f32[128*nsp*96]
    size_t pc=o;   o += (size_t)nsp*1572864; // pctx  f32[128*nsp*48*64]
    size_t kv=o;   o += (size_t)g*8388608;   // KV    bf16[32768][g*128]
    if (o <= ws_size || ci == 6){
      G=g; NSP=nsp;
      oXB=xb; oWIP=wip; oBIP=bip; oWO=wo; oEN=en; oCS=cs; oQA=qa; oOA=oa; oTK=tk; oSEL=sl;
      oAQ=aq; oCTXB=cb; oPML=pm; oPCTX=pc; oKV=kv;
      break;
    }
  }

  u16*   xb     = (u16*)(ws + oXB);
  u16*   ipwb   = (u16*)(ws + oWIP);
  u16*   ipbb   = (u16*)(ws + oBIP);
  u16*   outwb  = (u16*)(ws + oWO);
  float* energy = (float*)(ws + oEN);
  float* colsum = (float*)(ws + oCS);
  float* qacc   = (float*)(ws + oQA);
  float* oacc   = (float*)(ws + oOA);
  int*   topk   = (int*)(ws + oTK);
  int*   sel    = (int*)(ws + oSEL);
  u16*   Aq     = (u16*)(ws + oAQ);
  u16*   ctxb   = (u16*)(ws + oCTXB);
  float* pml    = (float*)(ws + oPML);
  float* pctx   = (float*)(ws + oPCTX);
  u16*   KV     = (u16*)(ws + oKV);

  hipMemsetAsync(colsum, 0, 32768 + 2*1572864, stream);

  k_prep_all <<<12291, 256, 0, stream>>>(x, xb, energy, ipw, ipb, outw, ipwb, ipbb, outwb);
  k_stats  <<<264, 256, 0, stream>>>(xb, colsum, energy, topk, sel);
  k_gather_q<<<dim3(8,48), 256, 0, stream>>>(x, topk, Aq);

  // Q = Aq @ Wq^T   split-K f32 accum; bias+scale folded into k_attn's fragment build
  k_gemm_sk <<<dim3(24,8), 256, 0, stream>>>(Aq, ipwb, qacc);

  if (G == 16){
    const int nt = 64/NSP;
    k_kvgemm6 <<<1024, 512, 0, stream>>>(xb,
        ipwb + (size_t)1024*1024, ipwb + (size_t)2048*1024,
        ipbb + 1024, ipbb + 2048, KV);
    k_attn <<<dim3(128, NSP), 64, 0, stream>>>(qacc, ipb, KV, pctx, pml, 16, 0, 2048, 1024, nt, NSP);
  } else {
    const int nchunk = 16 / G;
    const int ncols = G*128, half = G*64, nt = 64/NSP;
    for (int c=0; c<nchunk; ++c){
      int hg0 = c*G;
      k_gemm <<<G*256, 256, 0, stream>>>(
          xb,
          ipwb + (size_t)(1024 + hg0*64)*1024,
          ipwb + (size_t)(2048 + hg0*64)*1024,
          ipbb + 1024 + hg0*64,
          ipbb + 2048 + hg0*64,
          KV, G, ncols, half, 1.0f);
      k_attn <<<dim3(8*G, NSP), 64, 0, stream>>>(qacc, ipb, KV, pctx, pml, G, hg0, ncols, half, nt, NSP);
    }
  }

  k_combine<<<dim3(128,48), 64, 0, stream>>>(pctx, pml, ctxb, NSP);

  // out_sel = ctx @ Wo^T   split-K f32 accum, bias at finalize
  k_gemm_sk <<<dim3(24,8), 256, 0, stream>>>(ctxb, outwb, oacc);

  k_finalize<<<32768, 256, 0, stream>>>(oacc, outb, colsum, sel, out);
}

// Round 16
// 367.000 us; speedup vs baseline: 7.3595x; 1.0097x over previous
//
#include <hip/hip_runtime.h>

using u16 = unsigned short;
using u32 = unsigned int;
using u64 = unsigned long long;
typedef __attribute__((ext_vector_type(8))) short s16x8;
typedef __attribute__((ext_vector_type(4))) short s16x4;
typedef __attribute__((ext_vector_type(4))) float f32x4;

__device__ __forceinline__ float bf2f(u16 u){ return __uint_as_float(((u32)u)<<16); }
__device__ __forceinline__ u16 f2bf(float f){
  u32 u = __float_as_uint(f);
  u += 0x7fffu + ((u>>16)&1u);
  return (u16)(u>>16);
}
__device__ __forceinline__ void gl_lds16(const void* g, void* l){
  __builtin_amdgcn_global_load_lds((const __attribute__((address_space(1))) void*)g,
                                   (__attribute__((address_space(3))) void*)l, 16, 0, 0);
}

// ---------------- fused: x fp32->bf16 + energy (blocks 0..8191) | weight cvt (blocks 8192..12290) ----------------
__global__ __launch_bounds__(256) void k_prep_all(const float* __restrict__ x, u16* __restrict__ xb,
                                                  float* __restrict__ energy,
                                                  const float* __restrict__ ipw, const float* __restrict__ ipb,
                                                  const float* __restrict__ outw,
                                                  u16* __restrict__ ipwb, u16* __restrict__ ipbb,
                                                  u16* __restrict__ outwb){
  int bid = blockIdx.x;
  if (bid < 8192){
    int tok = bid*4 + (threadIdx.x>>6);
    int lane = threadIdx.x & 63;
    const float* p = x + (size_t)tok*1024 + lane*16;
    float4 a[4];
    #pragma unroll
    for (int j=0;j<4;++j) a[j] = ((const float4*)p)[j];
    float s = 0.f;
    s16x8 o0, o1;
    #pragma unroll
    for (int j=0;j<2;++j){
      o0[j*4+0]=(short)f2bf(a[j].x); o0[j*4+1]=(short)f2bf(a[j].y);
      o0[j*4+2]=(short)f2bf(a[j].z); o0[j*4+3]=(short)f2bf(a[j].w);
    }
    #pragma unroll
    for (int j=0;j<2;++j){
      o1[j*4+0]=(short)f2bf(a[2+j].x); o1[j*4+1]=(short)f2bf(a[2+j].y);
      o1[j*4+2]=(short)f2bf(a[2+j].z); o1[j*4+3]=(short)f2bf(a[2+j].w);
    }
    #pragma unroll
    for (int j=0;j<4;++j){
      s += a[j].x*a[j].x + a[j].y*a[j].y + a[j].z*a[j].z + a[j].w*a[j].w;
    }
    u16* xo = xb + (size_t)tok*1024 + lane*16;
    *(s16x8*)xo = o0;
    *(s16x8*)(xo+8) = o1;
    #pragma unroll
    for (int off=32; off; off>>=1) s += __shfl_xor(s, off);
    if (lane==0) energy[tok] = s;
    return;
  }
  int b2 = bid - 8192;
  const float* src; u16* dst; int n; int base;
  if (b2 < 3072){ src=ipw; dst=ipwb; n=3145728; base=b2; }
  else if (b2 < 3075){ src=ipb; dst=ipbb; n=3072; base=b2-3072; }
  else { src=outw; dst=outwb; n=1048576; base=b2-3075; }
  int i = (base*256 + threadIdx.x)*4;
  if (i >= n) return;
  float4 v = *(const float4*)(src + i);
  s16x4 o;
  o[0]=(short)f2bf(v.x); o[1]=(short)f2bf(v.y); o[2]=(short)f2bf(v.z); o[3]=(short)f2bf(v.w);
  *(s16x4*)(dst + i) = o;
}

// ---------------- fused stats: colsum (blocks 0..255) + top-41 (blocks 256..263, 1 barrier/iter) ----------------
__global__ __launch_bounds__(256) void k_stats(const u16* __restrict__ xb, float* __restrict__ colsum,
                                               const float* __restrict__ energy, int* __restrict__ topk,
                                               int* __restrict__ sel){
  if (blockIdx.x < 256){
    int b = blockIdx.x >> 5, sc = blockIdx.x & 31;
    int t = threadIdx.x;
    float acc[4] = {0.f,0.f,0.f,0.f};
    for (int s = sc*128; s < sc*128+128; ++s){
      s16x4 v = *(const s16x4*)(xb + ((size_t)b*4096 + s)*1024 + t*4);
      #pragma unroll
      for (int i=0;i<4;++i) acc[i] += bf2f((u16)v[i]);
    }
    #pragma unroll
    for (int i=0;i<4;++i) atomicAdd(&colsum[b*1024 + t*4 + i], acc[i]);
    return;
  }
  int b = blockIdx.x - 256;
  int t = threadIdx.x;
  int lane = t & 63, wid = t >> 6;
  __shared__ u64 wmax[2][4];
  u64 v[16];
  #pragma unroll
  for (int i=0;i<16;++i){
    u32 tok = i*256 + t;
    float e = energy[b*4096 + tok];
    v[i] = ((u64)__float_as_uint(e) << 32) | (u32)(~tok);
    sel[b*4096 + tok] = -1;
  }
  __syncthreads();
  for (int it=0; it<41; ++it){
    u64 m = v[0];
    #pragma unroll
    for (int i=1;i<16;++i) m = v[i] > m ? v[i] : m;
    #pragma unroll
    for (int off=32; off; off>>=1){
      u64 o = __shfl_xor(m, off);
      m = o > m ? o : m;
    }
    if (lane==0) wmax[it&1][wid] = m;
    __syncthreads();
    u64 g = wmax[it&1][0];
    #pragma unroll
    for (int w=1;w<4;++w) g = wmax[it&1][w] > g ? wmax[it&1][w] : g;
    u32 tok = (~(u32)g) & 4095u;
    if (t==0){ topk[b*64+it] = (int)tok; sel[b*4096 + tok] = it; }
    #pragma unroll
    for (int i=0;i<16;++i){
      if ((u32)(i*256 + t) == tok) v[i] = 0;
    }
  }
}

// ---------------- gather selected x rows -> Aq bf16 [8*48][1024], zero-pad qi>=41 ----------------
__global__ __launch_bounds__(256) void k_gather_q(const float* __restrict__ x, const int* __restrict__ topk,
                                                  u16* __restrict__ Aq){
  int b = blockIdx.x, qi = blockIdx.y, t = threadIdx.x;
  size_t dst = ((size_t)(b*48+qi))*1024 + t*4;
  if (qi >= 41){ s16x4 z = {0,0,0,0}; *(s16x4*)&Aq[dst] = z; return; }
  int tok = topk[b*64+qi];
  float4 v = *(const float4*)(x + ((size_t)b*4096 + tok)*1024 + t*4);
  s16x4 o;
  o[0]=(short)f2bf(v.x); o[1]=(short)f2bf(v.y); o[2]=(short)f2bf(v.z); o[3]=(short)f2bf(v.w);
  *(s16x4*)&Aq[dst] = o;
}

// ---------------- generalized bf16 GEMM (m97 structure), kept for small-ws fallback KV path ----------------
__global__ __launch_bounds__(256) void k_gemm(const u16* __restrict__ A, const u16* __restrict__ Bk,
                                              const u16* __restrict__ Bv,
                                              const u16* __restrict__ biask, const u16* __restrict__ biasv,
                                              u16* __restrict__ C, int nbn, int ncols, int half, float cscale){
  __shared__ u16 As[128*64];
  __shared__ u16 Bs[128*64];
  const int tid = threadIdx.x;
  const int bn = blockIdx.x % nbn;
  const int bm = blockIdx.x / nbn;
  const int m0 = bm*128, n0 = bn*128;
  const u16* Bbase  = (n0 < half) ? (Bk + (size_t)n0*1024) : (Bv + (size_t)(n0-half)*1024);
  const u16* biasp  = (n0 < half) ? (biask + n0) : (biasv + (n0-half));
  const int lane = tid & 63;
  const int wave = tid >> 6;
  const int wr = wave >> 1, wc = wave & 1;
  const int fr = lane & 15;
  const int fq = lane >> 4;
  f32x4 acc[4][4] = {};
  for (int k0 = 0; k0 < 1024; k0 += 64){
    __syncthreads();
    #pragma unroll
    for (int j=0;j<4;++j){
      int idx = j*256 + tid;
      int r = idx>>3; int cc = (idx&7)*8;
      gl_lds16(A + (size_t)(m0+r)*1024 + k0 + cc, &As[r*64+cc]);
    }
    #pragma unroll
    for (int j=0;j<4;++j){
      int idx = j*256 + tid;
      int r = idx>>3; int cc = (idx&7)*8;
      gl_lds16(Bbase + (size_t)r*1024 + k0 + cc, &Bs[r*64+cc]);
    }
    __syncthreads();
    #pragma unroll
    for (int kk=0; kk<64; kk+=32){
      s16x8 af[4], bfv[4];
      #pragma unroll
      for (int m=0;m<4;++m) af[m] = *(const s16x8*)&As[(wr*64 + m*16 + fr)*64 + kk + fq*8];
      #pragma unroll
      for (int n=0;n<4;++n) bfv[n] = *(const s16x8*)&Bs[(wc*64 + n*16 + fr)*64 + kk + fq*8];
      #pragma unroll
      for (int m=0;m<4;++m)
        #pragma unroll
        for (int n=0;n<4;++n)
          acc[m][n] = __builtin_amdgcn_mfma_f32_16x16x32_bf16(af[m], bfv[n], acc[m][n], 0,0,0);
    }
  }
  #pragma unroll
  for (int n=0;n<4;++n){
    int cl = wc*64 + n*16 + fr;
    int col = n0 + cl;
    float bvv = bf2f(biasp[cl]);
    #pragma unroll
    for (int m=0;m<4;++m){
      int rowb = m0 + wr*64 + m*16 + fq*4;
      f32x4 v = acc[m][n];
      #pragma unroll
      for (int i=0;i<4;++i)
        C[(size_t)(rowb+i)*ncols + col] = f2bf((v[i]+bvv)*cscale);
    }
  }
}

// ---------------- split-K small GEMM: grid (24, 8), K=128/chunk; f32 atomicAdd accum (no bias) ----------------
__global__ __launch_bounds__(256) void k_gemm_sk(const u16* __restrict__ A, const u16* __restrict__ B,
                                                 float* __restrict__ Cacc){
  __shared__ u16 As[128*64];
  __shared__ u16 Bs[128*64];
  const int tid = threadIdx.x;
  const int bn = blockIdx.x & 7;
  const int bm = blockIdx.x >> 3;
  const int kc = blockIdx.y;
  const int m0 = bm*128, n0 = bn*128;
  const u16* Bbase = B + (size_t)n0*1024;
  const int lane = tid & 63;
  const int wave = tid >> 6;
  const int wr = wave >> 1, wc = wave & 1;
  const int fr = lane & 15;
  const int fq = lane >> 4;
  f32x4 acc[4][4] = {};
  for (int k0 = kc*128; k0 < kc*128+128; k0 += 64){
    __syncthreads();
    #pragma unroll
    for (int j=0;j<4;++j){
      int idx = j*256 + tid;
      int r = idx>>3; int cc = (idx&7)*8;
      gl_lds16(A + (size_t)(m0+r)*1024 + k0 + cc, &As[r*64+cc]);
    }
    #pragma unroll
    for (int j=0;j<4;++j){
      int idx = j*256 + tid;
      int r = idx>>3; int cc = (idx&7)*8;
      gl_lds16(Bbase + (size_t)r*1024 + k0 + cc, &Bs[r*64+cc]);
    }
    __syncthreads();
    #pragma unroll
    for (int kk=0; kk<64; kk+=32){
      s16x8 af[4], bfv[4];
      #pragma unroll
      for (int m=0;m<4;++m) af[m] = *(const s16x8*)&As[(wr*64 + m*16 + fr)*64 + kk + fq*8];
      #pragma unroll
      for (int n=0;n<4;++n) bfv[n] = *(const s16x8*)&Bs[(wc*64 + n*16 + fr)*64 + kk + fq*8];
      #pragma unroll
      for (int m=0;m<4;++m)
        #pragma unroll
        for (int n=0;n<4;++n)
          acc[m][n] = __builtin_amdgcn_mfma_f32_16x16x32_bf16(af[m], bfv[n], acc[m][n], 0,0,0);
    }
  }
  #pragma unroll
  for (int n=0;n<4;++n){
    int col = n0 + wc*64 + n*16 + fr;
    #pragma unroll
    for (int m=0;m<4;++m){
      int rowb = m0 + wr*64 + m*16 + fq*4;
      f32x4 v = acc[m][n];
      #pragma unroll
      for (int i=0;i<4;++i)
        atomicAdd(&Cacc[(size_t)(rowb+i)*1024 + col], v[i]);
    }
  }
}

// ================= KV GEMM v4 (final): 256x256, BK=32, 8 waves, 4-slot LDS, reg-dbuf frags — best measured (166us) =================
__device__ __forceinline__ void stageA4(const u16* __restrict__ A, int m0, int k0, u16* slot, int tid){
  #pragma unroll
  for (int j=0;j<2;++j){
    int idx = j*512 + tid;
    int row = idx>>2;
    int sc = (idx&3) ^ ((row>>1)&3);
    gl_lds16(A + (size_t)(m0+row)*1024 + k0 + sc*8, slot + (size_t)idx*8);
  }
}
__device__ __forceinline__ void stageB4(const u16* __restrict__ B, int k0, u16* slot, int tid){
  #pragma unroll
  for (int j=0;j<2;++j){
    int idx = j*512 + tid;
    int row = idx>>2;
    int sc = (idx&3) ^ ((row>>1)&3);
    gl_lds16(B + (size_t)row*1024 + k0 + sc*8, slot + 8192 + (size_t)idx*8);
  }
}
__device__ __forceinline__ s16x8 fragA4(const u16* slot, int row, int fq){
  int pc = fq ^ ((row>>1)&3);
  return *(const s16x8*)(slot + row*32 + pc*8);
}
__device__ __forceinline__ s16x8 fragB4(const u16* slot, int row, int fq){
  int pc = fq ^ ((row>>1)&3);
  return *(const s16x8*)(slot + 8192 + row*32 + pc*8);
}

// 4 gl_lds per thread per tile; 3 tiles in flight -> steady vmcnt(8) retires tile T+1 (T+2,T+3 stay in flight)
#define KSTEP4(T, CA, CB, NA, NB)                                              \
  if ((T) < 29){                                                               \
    u16* ns = lds + (((T)+3)&3)*16384;                                         \
    stageA4(A, m0, ((T)+3)*32, ns, tid);                                       \
    stageB4(Bbase, ((T)+3)*32, ns, tid);                                       \
  }                                                                            \
  if ((T) < 29)      { asm volatile("s_waitcnt vmcnt(8)" ::: "memory"); }      \
  else if ((T)==29)  { asm volatile("s_waitcnt vmcnt(4)" ::: "memory"); }      \
  else if ((T)==30)  { asm volatile("s_waitcnt vmcnt(0)" ::: "memory"); }      \
  asm volatile("s_waitcnt lgkmcnt(0)" ::: "memory");                           \
  __builtin_amdgcn_sched_barrier(0);                                           \
  __builtin_amdgcn_s_barrier();                                                \
  __builtin_amdgcn_sched_barrier(0);                                           \
  if ((T) < 31){                                                               \
    const u16* rs = lds + (((T)+1)&3)*16384;                                   \
    _Pragma("unroll")                                                          \
    for (int m=0;m<8;++m) NA[m] = fragA4(rs, wm*128 + m*16 + fr, fq);          \
    _Pragma("unroll")                                                          \
    for (int n=0;n<4;++n) NB[n] = fragB4(rs, wn*64 + n*16 + fr, fq);           \
  }                                                                            \
  __builtin_amdgcn_sched_barrier(0);                                           \
  __builtin_amdgcn_s_setprio(1);                                               \
  _Pragma("unroll")                                                            \
  for (int m=0;m<8;++m)                                                        \
    _Pragma("unroll")                                                          \
    for (int n=0;n<4;++n)                                                      \
      acc[m][n] = __builtin_amdgcn_mfma_f32_16x16x32_bf16(CA[m], CB[n], acc[m][n], 0,0,0); \
  __builtin_amdgcn_s_setprio(0);

__global__ __launch_bounds__(512) void k_kvgemm4(const u16* __restrict__ A, const u16* __restrict__ Bk,
                                                 const u16* __restrict__ Bv,
                                                 const u16* __restrict__ biask, const u16* __restrict__ biasv,
                                                 u16* __restrict__ C){
  __shared__ u16 lds[4*16384];
  const int tid = threadIdx.x;
  const int sbid = ((int)blockIdx.x & 7)*128 + ((int)blockIdx.x >> 3);
  const int bn = sbid & 7;
  const int bm = sbid >> 3;
  const int m0 = bm*256, n0 = bn*256;
  const u16* Bbase = (bn < 4) ? (Bk + (size_t)n0*1024) : (Bv + (size_t)(n0-1024)*1024);
  const u16* biasp = (bn < 4) ? (biask + n0) : (biasv + (n0-1024));
  const int lane = tid & 63, wid = tid >> 6;
  const int wm = wid >> 2, wn = wid & 3;
  const int fr = lane & 15, fq = lane >> 4;
  f32x4 acc[8][4] = {};
  s16x8 afr0[8], bfr0[4], afr1[8], bfr1[4];

  stageA4(A, m0, 0, lds, tid);            stageB4(Bbase, 0, lds, tid);
  stageA4(A, m0, 32, lds+16384, tid);     stageB4(Bbase, 32, lds+16384, tid);
  stageA4(A, m0, 64, lds+2*16384, tid);   stageB4(Bbase, 64, lds+2*16384, tid);
  asm volatile("s_waitcnt vmcnt(8)" ::: "memory");
  __builtin_amdgcn_sched_barrier(0);
  __builtin_amdgcn_s_barrier();
  __builtin_amdgcn_sched_barrier(0);
  #pragma unroll
  for (int m=0;m<8;++m) afr0[m] = fragA4(lds, wm*128 + m*16 + fr, fq);
  #pragma unroll
  for (int n=0;n<4;++n) bfr0[n] = fragB4(lds, wn*64 + n*16 + fr, fq);

  for (int t=0; t<32; t+=2){
    KSTEP4(t,   afr0, bfr0, afr1, bfr1);
    KSTEP4(t+1, afr1, bfr1, afr0, bfr0);
  }

  u16* eLDS = lds;
  #pragma unroll
  for (int h=0; h<2; ++h){
    __syncthreads();
    if (wm == h){
      #pragma unroll
      for (int n=0;n<4;++n){
        int cl = wn*64 + n*16 + fr;
        float bvv = bf2f(biasp[cl]);
        #pragma unroll
        for (int m=0;m<8;++m){
          #pragma unroll
          for (int i=0;i<4;++i){
            int r = m*16 + fq*4 + i;
            eLDS[r*256 + cl] = f2bf(acc[m][n][i] + bvv);
          }
        }
      }
    }
    __syncthreads();
    #pragma unroll
    for (int j=0;j<8;++j){
      int e = j*512 + tid;
      int row = e >> 5, ch = e & 31;
      *(s16x8*)(C + (size_t)(m0 + h*128 + row)*2048 + n0 + ch*8) = *(const s16x8*)&eLDS[row*256 + ch*8];
    }
  }
}

// ---------------- flash attention: Q built from qacc f32 + bias + scale in-register ----------------
__global__ __launch_bounds__(64) void k_attn(const float* __restrict__ qacc, const float* __restrict__ bq,
                                             const u16* __restrict__ KV,
                                             float* __restrict__ part_ctx, float* __restrict__ part_ml,
                                             int G, int hg0, int ncols, int half, int nt, int NSP){
  const int b = blockIdx.x / G, hl = blockIdx.x % G;
  const int h = hg0 + hl;
  const int bh = b*16 + h;
  const int sp = blockIdx.y;
  const int lane = threadIdx.x;
  const int fr = lane & 15, fq = lane >> 4;
  __shared__ u16 k_lds[64*72];
  __shared__ u16 v_lds[64*72];
  __shared__ u16 p_lds[48*72];
  s16x8 af[3][2];
  #pragma unroll
  for (int m=0;m<3;++m)
    #pragma unroll
    for (int kk=0;kk<2;++kk){
      const float* qa = qacc + ((size_t)(b*48 + m*16 + fr))*1024 + h*64 + kk*32 + fq*8;
      const float* bp = bq + h*64 + kk*32 + fq*8;
      s16x8 f;
      #pragma unroll
      for (int j=0;j<8;++j) f[j] = (short)f2bf((qa[j] + bp[j])*0.125f);
      af[m][kk] = f;
    }
  f32x4 acc_o[3][4] = {};
  float m_run[3][4], l_run[3][4];
  #pragma unroll
  for (int m=0;m<3;++m)
    #pragma unroll
    for (int i=0;i<4;++i){ m_run[m][i] = -3e38f; l_run[m][i] = 0.f; }

  for (int it=0; it<nt; ++it){
    int s0 = (sp*nt + it)*64;
    __syncthreads();
    #pragma unroll
    for (int j=0;j<8;++j){
      int r = j*8 + (lane>>3);
      int sg = (lane&7)*8;
      const u16* kp = KV + ((size_t)(b*4096 + s0 + r))*ncols + hl*64 + sg;
      *(s16x8*)&k_lds[r*72+sg] = *(const s16x8*)kp;
      *(s16x8*)&v_lds[r*72+sg] = *(const s16x8*)(kp+half);
    }
    __syncthreads();
    f32x4 sc4[3][4] = {};
    #pragma unroll
    for (int kk=0;kk<2;++kk){
      s16x8 bk[4];
      #pragma unroll
      for (int n=0;n<4;++n)
        bk[n] = *(const s16x8*)&k_lds[(n*16+fr)*72 + kk*32 + fq*8];
      #pragma unroll
      for (int m=0;m<3;++m)
        #pragma unroll
        for (int n=0;n<4;++n)
          sc4[m][n] = __builtin_amdgcn_mfma_f32_16x16x32_bf16(af[m][kk], bk[n], sc4[m][n], 0,0,0);
    }
    #pragma unroll
    for (int m=0;m<3;++m){
      #pragma unroll
      for (int i=0;i<4;++i){
        float rmax = fmaxf(fmaxf(sc4[m][0][i], sc4[m][1][i]), fmaxf(sc4[m][2][i], sc4[m][3][i]));
        #pragma unroll
        for (int off=1; off<16; off<<=1) rmax = fmaxf(rmax, __shfl_xor(rmax, off));
        float mnew = fmaxf(m_run[m][i], rmax);
        float alpha = __expf(m_run[m][i] - mnew);
        m_run[m][i] = mnew;
        float rsum = 0.f;
        #pragma unroll
        for (int n=0;n<4;++n){
          float p = __expf(sc4[m][n][i] - mnew);
          rsum += p;
          p_lds[(m*16 + fq*4 + i)*72 + n*16 + fr] = f2bf(p);
        }
        #pragma unroll
        for (int off=1; off<16; off<<=1) rsum += __shfl_xor(rsum, off);
        l_run[m][i] = l_run[m][i]*alpha + rsum;
        #pragma unroll
        for (int n=0;n<4;++n) acc_o[m][n][i] *= alpha;
      }
    }
    __syncthreads();
    #pragma unroll
    for (int kk=0;kk<2;++kk){
      s16x8 ap[3];
      #pragma unroll
      for (int m=0;m<3;++m)
        ap[m] = *(const s16x8*)&p_lds[(m*16+fr)*72 + kk*32 + fq*8];
      #pragma unroll
      for (int n=0;n<4;++n){
        s16x8 bv;
        #pragma unroll
        for (int i2=0;i2<8;++i2)
          bv[i2] = (short)v_lds[(kk*32 + fq*8 + i2)*72 + n*16 + fr];
        #pragma unroll
        for (int m=0;m<3;++m)
          acc_o[m][n] = __builtin_amdgcn_mfma_f32_16x16x32_bf16(ap[m], bv, acc_o[m][n], 0,0,0);
      }
    }
  }
  size_t pbase = ((size_t)(bh*NSP + sp))*48*64;
  #pragma unroll
  for (int m=0;m<3;++m)
    #pragma unroll
    for (int n=0;n<4;++n)
      #pragma unroll
      for (int i=0;i<4;++i){
        int qi = m*16 + fq*4 + i, d = n*16 + fr;
        part_ctx[pbase + (size_t)qi*64 + d] = acc_o[m][n][i];
      }
  if (fr==0){
    #pragma unroll
    for (int m=0;m<3;++m)
      #pragma unroll
      for (int i=0;i<4;++i){
        int qi = m*16 + fq*4 + i;
        part_ml[((size_t)(bh*NSP+sp))*96 + qi*2+0] = m_run[m][i];
        part_ml[((size_t)(bh*NSP+sp))*96 + qi*2+1] = l_run[m][i];
      }
  }
}

// ---------------- combine NSP partials per (bh, qi), write bf16 ctx (zero-pad qi>=41) ----------------
__global__ __launch_bounds__(64) void k_combine(const float* __restrict__ part_ctx, const float* __restrict__ part_ml,
                                                u16* __restrict__ ctxb, int NSP){
  int bh = blockIdx.x, qi = blockIdx.y;
  int b = bh>>4, h = bh&15;
  int lane = threadIdx.x;
  size_t dst = ((size_t)(b*48+qi))*1024 + h*64 + lane;
  if (qi >= 41){ ctxb[dst] = 0; return; }
  float M = -3e38f;
  for (int p=0;p<NSP;++p)
    M = fmaxf(M, part_ml[((size_t)(bh*NSP+p))*96 + qi*2+0]);
  float l = 0.f, c = 0.f;
  for (int p=0;p<NSP;++p){
    float pm = part_ml[((size_t)(bh*NSP+p))*96 + qi*2+0];
    float pl = part_ml[((size_t)(bh*NSP+p))*96 + qi*2+1];
    float w = __expf(pm-M);
    l += pl*w;
    c += w * part_ctx[((size_t)(bh*NSP+p))*48*64 + (size_t)qi*64 + lane];
  }
  ctxb[dst] = f2bf(c / l);
}

// ---------------- finalize: selected rows = oacc + out_b (f32), others = per-batch mean ----------------
__global__ __launch_bounds__(256) void k_finalize(const float* __restrict__ oacc, const float* __restrict__ outb,
                                                  const float* __restrict__ colsum,
                                                  const int* __restrict__ sel, float* __restrict__ out){
  int row = blockIdx.x;
  int b = row >> 12;
  int t = threadIdx.x;
  int s = sel[row];
  float4 o;
  if (s >= 0){
    float4 a = *(const float4*)(oacc + ((size_t)(b*48+s))*1024 + t*4);
    float4 bb = *(const float4*)(outb + t*4);
    o.x = a.x+bb.x; o.y = a.y+bb.y; o.z = a.z+bb.z; o.w = a.w+bb.w;
  } else {
    o = *(const float4*)(colsum + b*1024 + t*4);
    o.x *= (1.f/4096.f); o.y *= (1.f/4096.f); o.z *= (1.f/4096.f); o.w *= (1.f/4096.f);
  }
  *(float4*)(out + (size_t)row*1024 + t*4) = o;
}

extern "C" void kernel_launch(void* const* d_in, const int* in_sizes, int n_in,
                              void* d_out, int out_size, void* d_ws, size_t ws_size,
                              hipStream_t stream) {
  const float* x    = (const float*)d_in[0];
  const float* ipw  = (const float*)d_in[1];
  const float* ipb  = (const float*)d_in[2];
  const float* outw = (const float*)d_in[3];
  const float* outb = (const float*)d_in[4];
  float* out = (float*)d_out;
  char* ws = (char*)d_ws;

  // ---- ws-adaptive config: G heads per KV chunk, NSP key-splits for attention ----
  const int cfgG[7]   = {16, 8, 4, 2, 1, 1, 1};
  const int cfgNSP[7] = {16,16,16,16,16, 4, 2};
  int G = 1, NSP = 2;
  size_t oXB=0,oWIP=0,oBIP=0,oWO=0,oEN=0,oCS=0,oQA=0,oOA=0,oTK=0,oSEL=0,oAQ=0,oCTXB=0,oPML=0,oPCTX=0,oKV=0;
  for (int ci=0; ci<7; ++ci){
    int g = cfgG[ci], nsp = cfgNSP[ci];
    size_t o = 0;
    size_t xb=o;   o += 67108864;            // xb    bf16[32768][1024]
    size_t wip=o;  o += 6291456;             // ipwb  bf16[3072][1024]
    size_t bip=o;  o += 6144;                // ipbb  bf16[3072]
    size_t wo=o;   o += 2097152;             // outwb bf16[1024][1024]
    size_t en=o;   o += 131072;              // energy f32[32768]
    size_t cs=o;   o += 32768;               // colsum f32[8*1024], contiguous with qacc+oacc for one memset
    size_t qa=o;   o += 1572864;             // qacc  f32[384][1024]
    size_t oa=o;   o += 1572864;             // oacc  f32[384][1024]
    size_t tk=o;   o += 2048;                // topk  int[8*64]
    size_t sl=o;   o += 131072;              // sel   int[32768]
    size_t aq=o;   o += 786432;              // Aq    bf16[384][1024]
    size_t cb=o;   o += 786432;              // ctxb  bf16[384][1024]
    size_t pm=o;   o += (size_t)nsp*49152;   // pml   f32[128*nsp*96]
    size_t pc=o;   o += (size_t)nsp*1572864; // pctx  f32[128*nsp*48*64]
    size_t kv=o;   o += (size_t)g*8388608;   // KV    bf16[32768][g*128]
    if (o <= ws_size || ci == 6){
      G=g; NSP=nsp;
      oXB=xb; oWIP=wip; oBIP=bip; oWO=wo; oEN=en; oCS=cs; oQA=qa; oOA=oa; oTK=tk; oSEL=sl;
      oAQ=aq; oCTXB=cb; oPML=pm; oPCTX=pc; oKV=kv;
      break;
    }
  }

  u16*   xb     = (u16*)(ws + oXB);
  u16*   ipwb   = (u16*)(ws + oWIP);
  u16*   ipbb   = (u16*)(ws + oBIP);
  u16*   outwb  = (u16*)(ws + oWO);
  float* energy = (float*)(ws + oEN);
  float* colsum = (float*)(ws + oCS);
  float* qacc   = (float*)(ws + oQA);
  float* oacc   = (float*)(ws + oOA);
  int*   topk   = (int*)(ws + oTK);
  int*   sel    = (int*)(ws + oSEL);
  u16*   Aq     = (u16*)(ws + oAQ);
  u16*   ctxb   = (u16*)(ws + oCTXB);
  float* pml    = (float*)(ws + oPML);
  float* pctx   = (float*)(ws + oPCTX);
  u16*   KV     = (u16*)(ws + oKV);

  hipMemsetAsync(colsum, 0, 32768 + 2*1572864, stream);

  k_prep_all <<<12291, 256, 0, stream>>>(x, xb, energy, ipw, ipb, outw, ipwb, ipbb, outwb);
  k_stats  <<<264, 256, 0, stream>>>(xb, colsum, energy, topk, sel);
  k_gather_q<<<dim3(8,48), 256, 0, stream>>>(x, topk, Aq);

  // Q = Aq @ Wq^T   split-K f32 accum; bias+scale folded into k_attn's fragment build
  k_gemm_sk <<<dim3(24,8), 256, 0, stream>>>(Aq, ipwb, qacc);

  if (G == 16){
    const int nt = 64/NSP;
    k_kvgemm4 <<<1024, 512, 0, stream>>>(xb,
        ipwb + (size_t)1024*1024, ipwb + (size_t)2048*1024,
        ipbb + 1024, ipbb + 2048, KV);
    k_attn <<<dim3(128, NSP), 64, 0, stream>>>(qacc, ipb, KV, pctx, pml, 16, 0, 2048, 1024, nt, NSP);
  } else {
    const int nchunk = 16 / G;
    const int ncols = G*128, half = G*64, nt = 64/NSP;
    for (int c=0; c<nchunk; ++c){
      int hg0 = c*G;
      k_gemm <<<G*256, 256, 0, stream>>>(
          xb,
          ipwb + (size_t)(1024 + hg0*64)*1024,
          ipwb + (size_t)(2048 + hg0*64)*1024,
          ipbb + 1024 + hg0*64,
          ipbb + 2048 + hg0*64,
          KV, G, ncols, half, 1.0f);
      k_attn <<<dim3(8*G, NSP), 64, 0, stream>>>(qacc, ipb, KV, pctx, pml, G, hg0, ncols, half, nt, NSP);
    }
  }

  k_combine<<<dim3(128,48), 64, 0, stream>>>(pctx, pml, ctxb, NSP);

  // out_sel = ctx @ Wo^T   split-K f32 accum, bias at finalize
  k_gemm_sk <<<dim3(24,8), 256, 0, stream>>>(ctxb, outwb, oacc);

  k_finalize<<<32768, 256, 0, stream>>>(oacc, outb, colsum, sel, out);
}

// Round 17
// 365.964 us; speedup vs baseline: 7.3804x; 1.0028x over previous
//
#include <hip/hip_runtime.h>

using u16 = unsigned short;
using u32 = unsigned int;
using u64 = unsigned long long;
typedef __attribute__((ext_vector_type(8))) short s16x8;
typedef __attribute__((ext_vector_type(4))) short s16x4;
typedef __attribute__((ext_vector_type(4))) float f32x4;

#define QPLANE 393216   // 384*1024 floats per split-K partial plane

__device__ __forceinline__ float bf2f(u16 u){ return __uint_as_float(((u32)u)<<16); }
__device__ __forceinline__ u16 f2bf(float f){
  u32 u = __float_as_uint(f);
  u += 0x7fffu + ((u>>16)&1u);
  return (u16)(u>>16);
}
__device__ __forceinline__ void gl_lds16(const void* g, void* l){
  __builtin_amdgcn_global_load_lds((const __attribute__((address_space(1))) void*)g,
                                   (__attribute__((address_space(3))) void*)l, 16, 0, 0);
}

// ---------------- fused: x fp32->bf16 + energy (blocks 0..8191) | weight cvt (blocks 8192..12290) ----------------
__global__ __launch_bounds__(256) void k_prep_all(const float* __restrict__ x, u16* __restrict__ xb,
                                                  float* __restrict__ energy,
                                                  const float* __restrict__ ipw, const float* __restrict__ ipb,
                                                  const float* __restrict__ outw,
                                                  u16* __restrict__ ipwb, u16* __restrict__ ipbb,
                                                  u16* __restrict__ outwb){
  int bid = blockIdx.x;
  if (bid < 8192){
    int tok = bid*4 + (threadIdx.x>>6);
    int lane = threadIdx.x & 63;
    const float* p = x + (size_t)tok*1024 + lane*16;
    float4 a[4];
    #pragma unroll
    for (int j=0;j<4;++j) a[j] = ((const float4*)p)[j];
    float s = 0.f;
    s16x8 o0, o1;
    #pragma unroll
    for (int j=0;j<2;++j){
      o0[j*4+0]=(short)f2bf(a[j].x); o0[j*4+1]=(short)f2bf(a[j].y);
      o0[j*4+2]=(short)f2bf(a[j].z); o0[j*4+3]=(short)f2bf(a[j].w);
    }
    #pragma unroll
    for (int j=0;j<2;++j){
      o1[j*4+0]=(short)f2bf(a[2+j].x); o1[j*4+1]=(short)f2bf(a[2+j].y);
      o1[j*4+2]=(short)f2bf(a[2+j].z); o1[j*4+3]=(short)f2bf(a[2+j].w);
    }
    #pragma unroll
    for (int j=0;j<4;++j){
      s += a[j].x*a[j].x + a[j].y*a[j].y + a[j].z*a[j].z + a[j].w*a[j].w;
    }
    u16* xo = xb + (size_t)tok*1024 + lane*16;
    *(s16x8*)xo = o0;
    *(s16x8*)(xo+8) = o1;
    #pragma unroll
    for (int off=32; off; off>>=1) s += __shfl_xor(s, off);
    if (lane==0) energy[tok] = s;
    return;
  }
  int b2 = bid - 8192;
  const float* src; u16* dst; int n; int base;
  if (b2 < 3072){ src=ipw; dst=ipwb; n=3145728; base=b2; }
  else if (b2 < 3075){ src=ipb; dst=ipbb; n=3072; base=b2-3072; }
  else { src=outw; dst=outwb; n=1048576; base=b2-3075; }
  int i = (base*256 + threadIdx.x)*4;
  if (i >= n) return;
  float4 v = *(const float4*)(src + i);
  s16x4 o;
  o[0]=(short)f2bf(v.x); o[1]=(short)f2bf(v.y); o[2]=(short)f2bf(v.z); o[3]=(short)f2bf(v.w);
  *(s16x4*)(dst + i) = o;
}

// ---------------- fused stats: colsum (blocks 0..255) + top-41 (blocks 256..263, 1 barrier/iter) ----------------
__global__ __launch_bounds__(256) void k_stats(const u16* __restrict__ xb, float* __restrict__ colsum,
                                               const float* __restrict__ energy, int* __restrict__ topk,
                                               int* __restrict__ sel){
  if (blockIdx.x < 256){
    int b = blockIdx.x >> 5, sc = blockIdx.x & 31;
    int t = threadIdx.x;
    float acc[4] = {0.f,0.f,0.f,0.f};
    for (int s = sc*128; s < sc*128+128; ++s){
      s16x4 v = *(const s16x4*)(xb + ((size_t)b*4096 + s)*1024 + t*4);
      #pragma unroll
      for (int i=0;i<4;++i) acc[i] += bf2f((u16)v[i]);
    }
    #pragma unroll
    for (int i=0;i<4;++i) atomicAdd(&colsum[b*1024 + t*4 + i], acc[i]);
    return;
  }
  int b = blockIdx.x - 256;
  int t = threadIdx.x;
  int lane = t & 63, wid = t >> 6;
  __shared__ u64 wmax[2][4];
  u64 v[16];
  #pragma unroll
  for (int i=0;i<16;++i){
    u32 tok = i*256 + t;
    float e = energy[b*4096 + tok];
    v[i] = ((u64)__float_as_uint(e) << 32) | (u32)(~tok);
    sel[b*4096 + tok] = -1;
  }
  __syncthreads();
  for (int it=0; it<41; ++it){
    u64 m = v[0];
    #pragma unroll
    for (int i=1;i<16;++i) m = v[i] > m ? v[i] : m;
    #pragma unroll
    for (int off=32; off; off>>=1){
      u64 o = __shfl_xor(m, off);
      m = o > m ? o : m;
    }
    if (lane==0) wmax[it&1][wid] = m;
    __syncthreads();
    u64 g = wmax[it&1][0];
    #pragma unroll
    for (int w=1;w<4;++w) g = wmax[it&1][w] > g ? wmax[it&1][w] : g;
    u32 tok = (~(u32)g) & 4095u;
    if (t==0){ topk[b*64+it] = (int)tok; sel[b*4096 + tok] = it; }
    #pragma unroll
    for (int i=0;i<16;++i){
      if ((u32)(i*256 + t) == tok) v[i] = 0;
    }
  }
}

// ---------------- gather selected x rows -> Aq bf16 [8*48][1024], zero-pad qi>=41 ----------------
__global__ __launch_bounds__(256) void k_gather_q(const float* __restrict__ x, const int* __restrict__ topk,
                                                  u16* __restrict__ Aq){
  int b = blockIdx.x, qi = blockIdx.y, t = threadIdx.x;
  size_t dst = ((size_t)(b*48+qi))*1024 + t*4;
  if (qi >= 41){ s16x4 z = {0,0,0,0}; *(s16x4*)&Aq[dst] = z; return; }
  int tok = topk[b*64+qi];
  float4 v = *(const float4*)(x + ((size_t)b*4096 + tok)*1024 + t*4);
  s16x4 o;
  o[0]=(short)f2bf(v.x); o[1]=(short)f2bf(v.y); o[2]=(short)f2bf(v.z); o[3]=(short)f2bf(v.w);
  *(s16x4*)&Aq[dst] = o;
}

// ---------------- generalized bf16 GEMM (m97 structure), kept for small-ws fallback KV path ----------------
__global__ __launch_bounds__(256) void k_gemm(const u16* __restrict__ A, const u16* __restrict__ Bk,
                                              const u16* __restrict__ Bv,
                                              const u16* __restrict__ biask, const u16* __restrict__ biasv,
                                              u16* __restrict__ C, int nbn, int ncols, int half, float cscale){
  __shared__ u16 As[128*64];
  __shared__ u16 Bs[128*64];
  const int tid = threadIdx.x;
  const int bn = blockIdx.x % nbn;
  const int bm = blockIdx.x / nbn;
  const int m0 = bm*128, n0 = bn*128;
  const u16* Bbase  = (n0 < half) ? (Bk + (size_t)n0*1024) : (Bv + (size_t)(n0-half)*1024);
  const u16* biasp  = (n0 < half) ? (biask + n0) : (biasv + (n0-half));
  const int lane = tid & 63;
  const int wave = tid >> 6;
  const int wr = wave >> 1, wc = wave & 1;
  const int fr = lane & 15;
  const int fq = lane >> 4;
  f32x4 acc[4][4] = {};
  for (int k0 = 0; k0 < 1024; k0 += 64){
    __syncthreads();
    #pragma unroll
    for (int j=0;j<4;++j){
      int idx = j*256 + tid;
      int r = idx>>3; int cc = (idx&7)*8;
      gl_lds16(A + (size_t)(m0+r)*1024 + k0 + cc, &As[r*64+cc]);
    }
    #pragma unroll
    for (int j=0;j<4;++j){
      int idx = j*256 + tid;
      int r = idx>>3; int cc = (idx&7)*8;
      gl_lds16(Bbase + (size_t)r*1024 + k0 + cc, &Bs[r*64+cc]);
    }
    __syncthreads();
    #pragma unroll
    for (int kk=0; kk<64; kk+=32){
      s16x8 af[4], bfv[4];
      #pragma unroll
      for (int m=0;m<4;++m) af[m] = *(const s16x8*)&As[(wr*64 + m*16 + fr)*64 + kk + fq*8];
      #pragma unroll
      for (int n=0;n<4;++n) bfv[n] = *(const s16x8*)&Bs[(wc*64 + n*16 + fr)*64 + kk + fq*8];
      #pragma unroll
      for (int m=0;m<4;++m)
        #pragma unroll
        for (int n=0;n<4;++n)
          acc[m][n] = __builtin_amdgcn_mfma_f32_16x16x32_bf16(af[m], bfv[n], acc[m][n], 0,0,0);
    }
  }
  #pragma unroll
  for (int n=0;n<4;++n){
    int cl = wc*64 + n*16 + fr;
    int col = n0 + cl;
    float bvv = bf2f(biasp[cl]);
    #pragma unroll
    for (int m=0;m<4;++m){
      int rowb = m0 + wr*64 + m*16 + fq*4;
      f32x4 v = acc[m][n];
      #pragma unroll
      for (int i=0;i<4;++i)
        C[(size_t)(rowb+i)*ncols + col] = f2bf((v[i]+bvv)*cscale);
    }
  }
}

// ---------------- split-K small GEMM, NO atomics: grid (24,4), K=256/chunk -> partial plane kc ----------------
__global__ __launch_bounds__(256) void k_gemm_sk(const u16* __restrict__ A, const u16* __restrict__ B,
                                                 float* __restrict__ Cpart){
  __shared__ u16 As[128*64];
  __shared__ u16 Bs[128*64];
  const int tid = threadIdx.x;
  const int bn = blockIdx.x & 7;
  const int bm = blockIdx.x >> 3;
  const int kc = blockIdx.y;
  const int m0 = bm*128, n0 = bn*128;
  const u16* Bbase = B + (size_t)n0*1024;
  const int lane = tid & 63;
  const int wave = tid >> 6;
  const int wr = wave >> 1, wc = wave & 1;
  const int fr = lane & 15;
  const int fq = lane >> 4;
  f32x4 acc[4][4] = {};
  for (int k0 = kc*256; k0 < kc*256+256; k0 += 64){
    __syncthreads();
    #pragma unroll
    for (int j=0;j<4;++j){
      int idx = j*256 + tid;
      int r = idx>>3; int cc = (idx&7)*8;
      gl_lds16(A + (size_t)(m0+r)*1024 + k0 + cc, &As[r*64+cc]);
    }
    #pragma unroll
    for (int j=0;j<4;++j){
      int idx = j*256 + tid;
      int r = idx>>3; int cc = (idx&7)*8;
      gl_lds16(Bbase + (size_t)r*1024 + k0 + cc, &Bs[r*64+cc]);
    }
    __syncthreads();
    #pragma unroll
    for (int kk=0; kk<64; kk+=32){
      s16x8 af[4], bfv[4];
      #pragma unroll
      for (int m=0;m<4;++m) af[m] = *(const s16x8*)&As[(wr*64 + m*16 + fr)*64 + kk + fq*8];
      #pragma unroll
      for (int n=0;n<4;++n) bfv[n] = *(const s16x8*)&Bs[(wc*64 + n*16 + fr)*64 + kk + fq*8];
      #pragma unroll
      for (int m=0;m<4;++m)
        #pragma unroll
        for (int n=0;n<4;++n)
          acc[m][n] = __builtin_amdgcn_mfma_f32_16x16x32_bf16(af[m], bfv[n], acc[m][n], 0,0,0);
    }
  }
  float* Cw = Cpart + (size_t)kc*QPLANE;
  #pragma unroll
  for (int n=0;n<4;++n){
    int col = n0 + wc*64 + n*16 + fr;
    #pragma unroll
    for (int m=0;m<4;++m){
      int rowb = m0 + wr*64 + m*16 + fq*4;
      f32x4 v = acc[m][n];
      #pragma unroll
      for (int i=0;i<4;++i)
        Cw[(size_t)(rowb+i)*1024 + col] = v[i];
    }
  }
}

// ================= KV GEMM v4 (final): 256x256, BK=32, 8 waves, 4-slot LDS, reg-dbuf frags — 166us/828TF =================
__device__ __forceinline__ void stageA4(const u16* __restrict__ A, int m0, int k0, u16* slot, int tid){
  #pragma unroll
  for (int j=0;j<2;++j){
    int idx = j*512 + tid;
    int row = idx>>2;
    int sc = (idx&3) ^ ((row>>1)&3);
    gl_lds16(A + (size_t)(m0+row)*1024 + k0 + sc*8, slot + (size_t)idx*8);
  }
}
__device__ __forceinline__ void stageB4(const u16* __restrict__ B, int k0, u16* slot, int tid){
  #pragma unroll
  for (int j=0;j<2;++j){
    int idx = j*512 + tid;
    int row = idx>>2;
    int sc = (idx&3) ^ ((row>>1)&3);
    gl_lds16(B + (size_t)row*1024 + k0 + sc*8, slot + 8192 + (size_t)idx*8);
  }
}
__device__ __forceinline__ s16x8 fragA4(const u16* slot, int row, int fq){
  int pc = fq ^ ((row>>1)&3);
  return *(const s16x8*)(slot + row*32 + pc*8);
}
__device__ __forceinline__ s16x8 fragB4(const u16* slot, int row, int fq){
  int pc = fq ^ ((row>>1)&3);
  return *(const s16x8*)(slot + 8192 + row*32 + pc*8);
}

// 4 gl_lds per thread per tile; 3 tiles in flight -> steady vmcnt(8) retires tile T+1 (T+2,T+3 stay in flight)
#define KSTEP4(T, CA, CB, NA, NB)                                              \
  if ((T) < 29){                                                               \
    u16* ns = lds + (((T)+3)&3)*16384;                                         \
    stageA4(A, m0, ((T)+3)*32, ns, tid);                                       \
    stageB4(Bbase, ((T)+3)*32, ns, tid);                                       \
  }                                                                            \
  if ((T) < 29)      { asm volatile("s_waitcnt vmcnt(8)" ::: "memory"); }      \
  else if ((T)==29)  { asm volatile("s_waitcnt vmcnt(4)" ::: "memory"); }      \
  else if ((T)==30)  { asm volatile("s_waitcnt vmcnt(0)" ::: "memory"); }      \
  asm volatile("s_waitcnt lgkmcnt(0)" ::: "memory");                           \
  __builtin_amdgcn_sched_barrier(0);                                           \
  __builtin_amdgcn_s_barrier();                                                \
  __builtin_amdgcn_sched_barrier(0);                                           \
  if ((T) < 31){                                                               \
    const u16* rs = lds + (((T)+1)&3)*16384;                                   \
    _Pragma("unroll")                                                          \
    for (int m=0;m<8;++m) NA[m] = fragA4(rs, wm*128 + m*16 + fr, fq);          \
    _Pragma("unroll")                                                          \
    for (int n=0;n<4;++n) NB[n] = fragB4(rs, wn*64 + n*16 + fr, fq);           \
  }                                                                            \
  __builtin_amdgcn_sched_barrier(0);                                           \
  __builtin_amdgcn_s_setprio(1);                                               \
  _Pragma("unroll")                                                            \
  for (int m=0;m<8;++m)                                                        \
    _Pragma("unroll")                                                          \
    for (int n=0;n<4;++n)                                                      \
      acc[m][n] = __builtin_amdgcn_mfma_f32_16x16x32_bf16(CA[m], CB[n], acc[m][n], 0,0,0); \
  __builtin_amdgcn_s_setprio(0);

__global__ __launch_bounds__(512) void k_kvgemm4(const u16* __restrict__ A, const u16* __restrict__ Bk,
                                                 const u16* __restrict__ Bv,
                                                 const u16* __restrict__ biask, const u16* __restrict__ biasv,
                                                 u16* __restrict__ C){
  __shared__ u16 lds[4*16384];
  const int tid = threadIdx.x;
  const int sbid = ((int)blockIdx.x & 7)*128 + ((int)blockIdx.x >> 3);
  const int bn = sbid & 7;
  const int bm = sbid >> 3;
  const int m0 = bm*256, n0 = bn*256;
  const u16* Bbase = (bn < 4) ? (Bk + (size_t)n0*1024) : (Bv + (size_t)(n0-1024)*1024);
  const u16* biasp = (bn < 4) ? (biask + n0) : (biasv + (n0-1024));
  const int lane = tid & 63, wid = tid >> 6;
  const int wm = wid >> 2, wn = wid & 3;
  const int fr = lane & 15, fq = lane >> 4;
  f32x4 acc[8][4] = {};
  s16x8 afr0[8], bfr0[4], afr1[8], bfr1[4];

  stageA4(A, m0, 0, lds, tid);            stageB4(Bbase, 0, lds, tid);
  stageA4(A, m0, 32, lds+16384, tid);     stageB4(Bbase, 32, lds+16384, tid);
  stageA4(A, m0, 64, lds+2*16384, tid);   stageB4(Bbase, 64, lds+2*16384, tid);
  asm volatile("s_waitcnt vmcnt(8)" ::: "memory");
  __builtin_amdgcn_sched_barrier(0);
  __builtin_amdgcn_s_barrier();
  __builtin_amdgcn_sched_barrier(0);
  #pragma unroll
  for (int m=0;m<8;++m) afr0[m] = fragA4(lds, wm*128 + m*16 + fr, fq);
  #pragma unroll
  for (int n=0;n<4;++n) bfr0[n] = fragB4(lds, wn*64 + n*16 + fr, fq);

  for (int t=0; t<32; t+=2){
    KSTEP4(t,   afr0, bfr0, afr1, bfr1);
    KSTEP4(t+1, afr1, bfr1, afr0, bfr0);
  }

  u16* eLDS = lds;
  #pragma unroll
  for (int h=0; h<2; ++h){
    __syncthreads();
    if (wm == h){
      #pragma unroll
      for (int n=0;n<4;++n){
        int cl = wn*64 + n*16 + fr;
        float bvv = bf2f(biasp[cl]);
        #pragma unroll
        for (int m=0;m<8;++m){
          #pragma unroll
          for (int i=0;i<4;++i){
            int r = m*16 + fq*4 + i;
            eLDS[r*256 + cl] = f2bf(acc[m][n][i] + bvv);
          }
        }
      }
    }
    __syncthreads();
    #pragma unroll
    for (int j=0;j<8;++j){
      int e = j*512 + tid;
      int row = e >> 5, ch = e & 31;
      *(s16x8*)(C + (size_t)(m0 + h*128 + row)*2048 + n0 + ch*8) = *(const s16x8*)&eLDS[row*256 + ch*8];
    }
  }
}

// ---------------- flash attention: Q built from 4 qacc partials + bias + scale in-register ----------------
__global__ __launch_bounds__(64) void k_attn(const float* __restrict__ qacc, const float* __restrict__ bq,
                                             const u16* __restrict__ KV,
                                             float* __restrict__ part_ctx, float* __restrict__ part_ml,
                                             int G, int hg0, int ncols, int half, int nt, int NSP){
  const int b = blockIdx.x / G, hl = blockIdx.x % G;
  const int h = hg0 + hl;
  const int bh = b*16 + h;
  const int sp = blockIdx.y;
  const int lane = threadIdx.x;
  const int fr = lane & 15, fq = lane >> 4;
  __shared__ u16 k_lds[64*72];
  __shared__ u16 v_lds[64*72];
  __shared__ u16 p_lds[48*72];
  s16x8 af[3][2];
  #pragma unroll
  for (int m=0;m<3;++m)
    #pragma unroll
    for (int kk=0;kk<2;++kk){
      const float* qa = qacc + ((size_t)(b*48 + m*16 + fr))*1024 + h*64 + kk*32 + fq*8;
      const float* bp = bq + h*64 + kk*32 + fq*8;
      s16x8 f;
      #pragma unroll
      for (int j=0;j<8;++j){
        float s = bp[j] + qa[j] + qa[QPLANE+j] + qa[2*QPLANE+j] + qa[3*QPLANE+j];
        f[j] = (short)f2bf(s*0.125f);
      }
      af[m][kk] = f;
    }
  f32x4 acc_o[3][4] = {};
  float m_run[3][4], l_run[3][4];
  #pragma unroll
  for (int m=0;m<3;++m)
    #pragma unroll
    for (int i=0;i<4;++i){ m_run[m][i] = -3e38f; l_run[m][i] = 0.f; }

  for (int it=0; it<nt; ++it){
    int s0 = (sp*nt + it)*64;
    __syncthreads();
    #pragma unroll
    for (int j=0;j<8;++j){
      int r = j*8 + (lane>>3);
      int sg = (lane&7)*8;
      const u16* kp = KV + ((size_t)(b*4096 + s0 + r))*ncols + hl*64 + sg;
      *(s16x8*)&k_lds[r*72+sg] = *(const s16x8*)kp;
      *(s16x8*)&v_lds[r*72+sg] = *(const s16x8*)(kp+half);
    }
    __syncthreads();
    f32x4 sc4[3][4] = {};
    #pragma unroll
    for (int kk=0;kk<2;++kk){
      s16x8 bk[4];
      #pragma unroll
      for (int n=0;n<4;++n)
        bk[n] = *(const s16x8*)&k_lds[(n*16+fr)*72 + kk*32 + fq*8];
      #pragma unroll
      for (int m=0;m<3;++m)
        #pragma unroll
        for (int n=0;n<4;++n)
          sc4[m][n] = __builtin_amdgcn_mfma_f32_16x16x32_bf16(af[m][kk], bk[n], sc4[m][n], 0,0,0);
    }
    #pragma unroll
    for (int m=0;m<3;++m){
      #pragma unroll
      for (int i=0;i<4;++i){
        float rmax = fmaxf(fmaxf(sc4[m][0][i], sc4[m][1][i]), fmaxf(sc4[m][2][i], sc4[m][3][i]));
        #pragma unroll
        for (int off=1; off<16; off<<=1) rmax = fmaxf(rmax, __shfl_xor(rmax, off));
        float mnew = fmaxf(m_run[m][i], rmax);
        float alpha = __expf(m_run[m][i] - mnew);
        m_run[m][i] = mnew;
        float rsum = 0.f;
        #pragma unroll
        for (int n=0;n<4;++n){
          float p = __expf(sc4[m][n][i] - mnew);
          rsum += p;
          p_lds[(m*16 + fq*4 + i)*72 + n*16 + fr] = f2bf(p);
        }
        #pragma unroll
        for (int off=1; off<16; off<<=1) rsum += __shfl_xor(rsum, off);
        l_run[m][i] = l_run[m][i]*alpha + rsum;
        #pragma unroll
        for (int n=0;n<4;++n) acc_o[m][n][i] *= alpha;
      }
    }
    __syncthreads();
    #pragma unroll
    for (int kk=0;kk<2;++kk){
      s16x8 ap[3];
      #pragma unroll
      for (int m=0;m<3;++m)
        ap[m] = *(const s16x8*)&p_lds[(m*16+fr)*72 + kk*32 + fq*8];
      #pragma unroll
      for (int n=0;n<4;++n){
        s16x8 bv;
        #pragma unroll
        for (int i2=0;i2<8;++i2)
          bv[i2] = (short)v_lds[(kk*32 + fq*8 + i2)*72 + n*16 + fr];
        #pragma unroll
        for (int m=0;m<3;++m)
          acc_o[m][n] = __builtin_amdgcn_mfma_f32_16x16x32_bf16(ap[m], bv, acc_o[m][n], 0,0,0);
      }
    }
  }
  size_t pbase = ((size_t)(bh*NSP + sp))*48*64;
  #pragma unroll
  for (int m=0;m<3;++m)
    #pragma unroll
    for (int n=0;n<4;++n)
      #pragma unroll
      for (int i=0;i<4;++i){
        int qi = m*16 + fq*4 + i, d = n*16 + fr;
        part_ctx[pbase + (size_t)qi*64 + d] = acc_o[m][n][i];
      }
  if (fr==0){
    #pragma unroll
    for (int m=0;m<3;++m)
      #pragma unroll
      for (int i=0;i<4;++i){
        int qi = m*16 + fq*4 + i;
        part_ml[((size_t)(bh*NSP+sp))*96 + qi*2+0] = m_run[m][i];
        part_ml[((size_t)(bh*NSP+sp))*96 + qi*2+1] = l_run[m][i];
      }
  }
}

// ---------------- combine NSP partials per (bh, qi), write bf16 ctx (zero-pad qi>=41) ----------------
__global__ __launch_bounds__(64) void k_combine(const float* __restrict__ part_ctx, const float* __restrict__ part_ml,
                                                u16* __restrict__ ctxb, int NSP){
  int bh = blockIdx.x, qi = blockIdx.y;
  int b = bh>>4, h = bh&15;
  int lane = threadIdx.x;
  size_t dst = ((size_t)(b*48+qi))*1024 + h*64 + lane;
  if (qi >= 41){ ctxb[dst] = 0; return; }
  float M = -3e38f;
  for (int p=0;p<NSP;++p)
    M = fmaxf(M, part_ml[((size_t)(bh*NSP+p))*96 + qi*2+0]);
  float l = 0.f, c = 0.f;
  for (int p=0;p<NSP;++p){
    float pm = part_ml[((size_t)(bh*NSP+p))*96 + qi*2+0];
    float pl = part_ml[((size_t)(bh*NSP+p))*96 + qi*2+1];
    float w = __expf(pm-M);
    l += pl*w;
    c += w * part_ctx[((size_t)(bh*NSP+p))*48*64 + (size_t)qi*64 + lane];
  }
  ctxb[dst] = f2bf(c / l);
}

// ---------------- finalize: selected rows = sum of 4 oacc partials + out_b (f32), others = mean ----------------
__global__ __launch_bounds__(256) void k_finalize(const float* __restrict__ oacc, const float* __restrict__ outb,
                                                  const float* __restrict__ colsum,
                                                  const int* __restrict__ sel, float* __restrict__ out){
  int row = blockIdx.x;
  int b = row >> 12;
  int t = threadIdx.x;
  int s = sel[row];
  float4 o;
  if (s >= 0){
    size_t idx = ((size_t)(b*48+s))*1024 + t*4;
    float4 a0 = *(const float4*)(oacc + idx);
    float4 a1 = *(const float4*)(oacc + QPLANE + idx);
    float4 a2 = *(const float4*)(oacc + 2*QPLANE + idx);
    float4 a3 = *(const float4*)(oacc + 3*QPLANE + idx);
    float4 bb = *(const float4*)(outb + t*4);
    o.x = a0.x+a1.x+a2.x+a3.x+bb.x;
    o.y = a0.y+a1.y+a2.y+a3.y+bb.y;
    o.z = a0.z+a1.z+a2.z+a3.z+bb.z;
    o.w = a0.w+a1.w+a2.w+a3.w+bb.w;
  } else {
    o = *(const float4*)(colsum + b*1024 + t*4);
    o.x *= (1.f/4096.f); o.y *= (1.f/4096.f); o.z *= (1.f/4096.f); o.w *= (1.f/4096.f);
  }
  *(float4*)(out + (size_t)row*1024 + t*4) = o;
}

extern "C" void kernel_launch(void* const* d_in, const int* in_sizes, int n_in,
                              void* d_out, int out_size, void* d_ws, size_t ws_size,
                              hipStream_t stream) {
  const float* x    = (const float*)d_in[0];
  const float* ipw  = (const float*)d_in[1];
  const float* ipb  = (const float*)d_in[2];
  const float* outw = (const float*)d_in[3];
  const float* outb = (const float*)d_in[4];
  float* out = (float*)d_out;
  char* ws = (char*)d_ws;

  // ---- ws-adaptive config: G heads per KV chunk, NSP key-splits for attention ----
  const int cfgG[7]   = {16, 8, 4, 2, 1, 1, 1};
  const int cfgNSP[7] = {16,16,16,16,16, 4, 2};
  int G = 1, NSP = 2;
  size_t oXB=0,oWIP=0,oBIP=0,oWO=0,oEN=0,oCS=0,oQA=0,oTK=0,oSEL=0,oAQ=0,oCTXB=0,oPML=0,oPCTX=0,oKV=0;
  for (int ci=0; ci<7; ++ci){
    int g = cfgG[ci], nsp = cfgNSP[ci];
    size_t o = 0;
    size_t xb=o;   o += 67108864;            // xb    bf16[32768][1024]
    size_t wip=o;  o += 6291456;             // ipwb  bf16[3072][1024]
    size_t bip=o;  o += 6144;                // ipbb  bf16[3072]
    size_t wo=o;   o += 2097152;             // outwb bf16[1024][1024]
    size_t en=o;   o += 131072;              // energy f32[32768]
    size_t cs=o;   o += 32768;               // colsum f32[8*1024] (only memset target)
    size_t qa=o;   o += 4*1572864;           // qacc  f32[4][384][1024] split-K partials
    size_t tk=o;   o += 2048;                // topk  int[8*64]
    size_t sl=o;   o += 131072;              // sel   int[32768]
    size_t aq=o;   o += 786432;              // Aq    bf16[384][1024]
    size_t cb=o;   o += 786432;              // ctxb  bf16[384][1024]
    size_t pm=o;   o += (size_t)nsp*49152;   // pml   f32[128*nsp*96]
    size_t pcsz = (size_t)nsp*1572864;
    if (pcsz < 4*1572864) pcsz = 4*1572864;  // pctx region also hosts oacc partials (aliased; pctx dead by then)
    size_t pc=o;   o += pcsz;                // pctx f32[128*nsp*48*64] / later oacc f32[4][384][1024]
    size_t kv=o;   o += (size_t)g*8388608;   // KV    bf16[32768][g*128]
    if (o <= ws_size || ci == 6){
      G=g; NSP=nsp;
      oXB=xb; oWIP=wip; oBIP=bip; oWO=wo; oEN=en; oCS=cs; oQA=qa; oTK=tk; oSEL=sl;
      oAQ=aq; oCTXB=cb; oPML=pm; oPCTX=pc; oKV=kv;
      break;
    }
  }

  u16*   xb     = (u16*)(ws + oXB);
  u16*   ipwb   = (u16*)(ws + oWIP);
  u16*   ipbb   = (u16*)(ws + oBIP);
  u16*   outwb  = (u16*)(ws + oWO);
  float* energy = (float*)(ws + oEN);
  float* colsum = (float*)(ws + oCS);
  float* qacc   = (float*)(ws + oQA);
  int*   topk   = (int*)(ws + oTK);
  int*   sel    = (int*)(ws + oSEL);
  u16*   Aq     = (u16*)(ws + oAQ);
  u16*   ctxb   = (u16*)(ws + oCTXB);
  float* pml    = (float*)(ws + oPML);
  float* pctx   = (float*)(ws + oPCTX);
  float* oacc   = (float*)(ws + oPCTX);   // aliased: pctx dead after k_combine
  u16*   KV     = (u16*)(ws + oKV);

  hipMemsetAsync(colsum, 0, 32768, stream);

  k_prep_all <<<12291, 256, 0, stream>>>(x, xb, energy, ipw, ipb, outw, ipwb, ipbb, outwb);
  k_stats  <<<264, 256, 0, stream>>>(xb, colsum, energy, topk, sel);
  k_gather_q<<<dim3(8,48), 256, 0, stream>>>(x, topk, Aq);

  // Q = Aq @ Wq^T  split-K partials (no atomics); bias+scale+sum folded into k_attn
  k_gemm_sk <<<dim3(24,4), 256, 0, stream>>>(Aq, ipwb, qacc);

  if (G == 16){
    const int nt = 64/NSP;
    k_kvgemm4 <<<1024, 512, 0, stream>>>(xb,
        ipwb + (size_t)1024*1024, ipwb + (size_t)2048*1024,
        ipbb + 1024, ipbb + 2048, KV);
    k_attn <<<dim3(128, NSP), 64, 0, stream>>>(qacc, ipb, KV, pctx, pml, 16, 0, 2048, 1024, nt, NSP);
  } else {
    const int nchunk = 16 / G;
    const int ncols = G*128, half = G*64, nt = 64/NSP;
    for (int c=0; c<nchunk; ++c){
      int hg0 = c*G;
      k_gemm <<<G*256, 256, 0, stream>>>(
          xb,
          ipwb + (size_t)(1024 + hg0*64)*1024,
          ipwb + (size_t)(2048 + hg0*64)*1024,
          ipbb + 1024 + hg0*64,
          ipbb + 2048 + hg0*64,
          KV, G, ncols, half, 1.0f);
      k_attn <<<dim3(8*G, NSP), 64, 0, stream>>>(qacc, ipb, KV, pctx, pml, G, hg0, ncols, half, nt, NSP);
    }
  }

  k_combine<<<dim3(128,48), 64, 0, stream>>>(pctx, pml, ctxb, NSP);

  // out_sel = ctx @ Wo^T  split-K partials into oacc (aliased over dead pctx); bias at finalize
  k_gemm_sk <<<dim3(24,4), 256, 0, stream>>>(ctxb, outwb, oacc);

  k_finalize<<<32768, 256, 0, stream>>>(oacc, outb, colsum, sel, out);
}